// Round 1
// baseline (724.828 us; speedup 1.0000x reference)
//
#include <hip/hip_runtime.h>

// ---------- types ----------
typedef __attribute__((ext_vector_type(8))) short short8;   // 8 bf16 (4 VGPR)
typedef __attribute__((ext_vector_type(4))) short short4v;  // 4 bf16
typedef __attribute__((ext_vector_type(4))) float float4v;  // 4 fp32

__device__ __forceinline__ float bf2f(short s) {
  union { float f; unsigned u; } cv; cv.u = ((unsigned)(unsigned short)s) << 16; return cv.f;
}
__device__ __forceinline__ short f2bf(float f) {   // RNE fp32->bf16, inputs never NaN
  union { float f; unsigned u; } cv; cv.f = f;
  unsigned u = cv.u;
  unsigned r = u + 0x7FFFu + ((u >> 16) & 1u);
  return (short)(r >> 16);
}
__device__ __forceinline__ float gelu_f(float v) {
  return 0.5f * v * (1.0f + erff(v * 0.70710678118654752440f));
}

// ---------- MFMA GEMM: C[m][n] = sum_k A[m][k] * BT[n][k]  (128x128 tile, BK=32) ----------
// A_FP32: A is fp32 (converted to bf16 while staging); else A is bf16.
// EPI: 0 = +bias, gelu, store bf16 ; 1 = +bias, store bf16 ; 2 = atomicAdd fp32 (split-K)
template<int A_FP32, int EPI>
__global__ __launch_bounds__(256) void gemm_bt(
    const void* __restrict__ A_, const short* __restrict__ BT,
    const float* __restrict__ bias, void* __restrict__ out,
    int lda, int ldb, int ldc, int kSteps, int kChunk,
    const int* __restrict__ seq_lens, int seqSkip)
{
  int m0 = blockIdx.y * 128;
  int n0 = blockIdx.x * 128;
  if (seqSkip) {               // rows are (b*4096 + t); skip tiles fully past seq_len
    int b = m0 >> 12, t = m0 & 4095;
    if (t >= seq_lens[b]) return;
  }
  int kBase = blockIdx.z * kChunk;

  __shared__ short As[128 * 32];
  __shared__ short Bs[128 * 32];

  int tid = threadIdx.x;
  int lane = tid & 63, wave = tid >> 6;
  int l15 = lane & 15, quad = lane >> 4;
  int wm = wave & 1, wn = wave >> 1;   // wave quadrant (64x64)

  float4v acc[4][4];
#pragma unroll
  for (int i = 0; i < 4; i++)
#pragma unroll
    for (int j = 0; j < 4; j++) acc[i][j] = 0;

  int r = tid >> 1;            // tile row handled by this thread for staging
  int off = (tid & 1) * 16;    // 16-element half of the 32-wide k slice

  for (int ks = 0; ks < kSteps; ++ks) {
    int kk = kBase + ks * 32;
    if (A_FP32) {
      const float* Af = (const float*)A_ + (size_t)(m0 + r) * lda + kk + off;
      float4v x0 = ((const float4v*)Af)[0];
      float4v x1 = ((const float4v*)Af)[1];
      float4v x2 = ((const float4v*)Af)[2];
      float4v x3 = ((const float4v*)Af)[3];
      short tmp[16];
#pragma unroll
      for (int j = 0; j < 4; j++) {
        tmp[j] = f2bf(x0[j]); tmp[4 + j] = f2bf(x1[j]);
        tmp[8 + j] = f2bf(x2[j]); tmp[12 + j] = f2bf(x3[j]);
      }
      *(short8*)&As[r * 32 + off] = *(short8*)tmp;
      *(short8*)&As[r * 32 + off + 8] = *(short8*)(tmp + 8);
    } else {
      const short* Ab = (const short*)A_ + (size_t)(m0 + r) * lda + kk + off;
      *(short8*)&As[r * 32 + off]     = ((const short8*)Ab)[0];
      *(short8*)&As[r * 32 + off + 8] = ((const short8*)Ab)[1];
    }
    {
      const short* Bb = BT + (size_t)(n0 + r) * ldb + kk + off;
      *(short8*)&Bs[r * 32 + off]     = ((const short8*)Bb)[0];
      *(short8*)&Bs[r * 32 + off + 8] = ((const short8*)Bb)[1];
    }
    __syncthreads();
    short8 af[4], bfr[4];
#pragma unroll
    for (int im = 0; im < 4; im++)
      af[im] = *(short8*)&As[(wm * 64 + im * 16 + l15) * 32 + quad * 8];
#pragma unroll
    for (int in = 0; in < 4; in++)
      bfr[in] = *(short8*)&Bs[(wn * 64 + in * 16 + l15) * 32 + quad * 8];
#pragma unroll
    for (int im = 0; im < 4; im++)
#pragma unroll
      for (int in = 0; in < 4; in++)
        acc[im][in] = __builtin_amdgcn_mfma_f32_16x16x32_bf16(af[im], bfr[in], acc[im][in], 0, 0, 0);
    __syncthreads();
  }

  // C/D layout: col = lane&15, row = quad*4 + reg  [guide §3, m89/m91-verified]
#pragma unroll
  for (int im = 0; im < 4; im++) {
#pragma unroll
    for (int in = 0; in < 4; in++) {
      int n = n0 + wn * 64 + in * 16 + l15;
#pragma unroll
      for (int reg = 0; reg < 4; reg++) {
        int m = m0 + wm * 64 + im * 16 + quad * 4 + reg;
        float v = acc[im][in][reg];
        if (EPI == 0) {
          v += bias[n]; v = gelu_f(v);
          ((short*)out)[(size_t)m * ldc + n] = f2bf(v);
        } else if (EPI == 1) {
          v += bias[n];
          ((short*)out)[(size_t)m * ldc + n] = f2bf(v);
        } else {
          atomicAdd((float*)out + (size_t)m * ldc + n, v);
        }
      }
    }
  }
}

// ---------- prep: weight transposes to bf16, power-table seeds ----------
__global__ void prep_kernel(const float* __restrict__ w1, const float* __restrict__ w2,
                            const float* __restrict__ A,
                            short* __restrict__ w1T, short* __restrict__ w2T,
                            float* __restrict__ Apow, float* __restrict__ Bpow,
                            short* __restrict__ P1, short* __restrict__ P1t,
                            short* __restrict__ P2t)
{
  int idx = blockIdx.x * 256 + threadIdx.x;
  if (idx < 1024 * 384) {                        // w1T[n][k] = w1[k][n]
    int n = idx / 384, k = idx % 384;
    w1T[idx] = f2bf(w1[k * 1024 + n]);
    return;
  }
  idx -= 1024 * 384;
  if (idx < 128 * 1024) {                        // w2T[n][k] = w2[k][n]
    int n = idx / 1024, k = idx % 1024;
    w2T[idx] = f2bf(w2[k * 128 + n]);
    return;
  }
  idx -= 128 * 1024;
  if (idx < 16384) {                             // identity: Apow[0], Bpow[0], P slots e=0
    int i = idx / 128, j = idx % 128;
    float idv = (i == j) ? 1.0f : 0.0f;
    Apow[idx] = idv;
    Bpow[idx] = idv;
    short bidv = f2bf(idv);
    P1[i * 8192 + 63 * 128 + j] = bidv;          // A^0 in column-block 63
    P1t[(63 * 128 + j) * 128 + i] = bidv;
    P2t[(63 * 128 + j) * 128 + i] = bidv;        // (A^64)^0
    return;
  }
  idx -= 16384;
  if (idx < 16384) {                             // A itself: Apow[1], P slots e=1
    int i = idx / 128, j = idx % 128;
    float av = A[idx];
    Apow[16384 + idx] = av;
    short ab = f2bf(av);
    P1[i * 8192 + 62 * 128 + j] = ab;
    P1t[(62 * 128 + j) * 128 + i] = ab;
  }
}

// ---------- power doubling round: for jp=1..m compute tab[m+jp] = tab[m] @ tab[jp] ----------
// tableId 1: tab = Apow (writes P1/P1t slots; at e==64 seeds Bpow[1] and P2t e=1)
// tableId 2: tab = Bpow (writes P2t slots)
__global__ __launch_bounds__(256) void power_round(
    float* __restrict__ tab, int m, int tableId,
    float* __restrict__ Bpow, short* __restrict__ P1,
    short* __restrict__ P1t, short* __restrict__ P2t)
{
  int jp = (blockIdx.x >> 4) + 1;
  int chunk = blockIdx.x & 15;
  int e = m + jp;
  const float* X = tab + (size_t)m * 16384;
  const float* Y = tab + (size_t)jp * 16384;
  float* C = tab + (size_t)e * 16384;

  __shared__ float Ys[16384];
  for (int i = threadIdx.x; i < 4096; i += 256)
    ((float4v*)Ys)[i] = ((const float4v*)Y)[i];
  __syncthreads();

  int col = threadIdx.x & 127;
  int rh = threadIdx.x >> 7;
  int rbase = chunk * 8 + rh * 4;
  float acc[4] = {0, 0, 0, 0};
  for (int k4 = 0; k4 < 32; ++k4) {
    float4v xv[4];
#pragma unroll
    for (int q = 0; q < 4; q++)
      xv[q] = *(const float4v*)&X[(rbase + q) * 128 + k4 * 4];
#pragma unroll
    for (int kk = 0; kk < 4; kk++) {
      float yv = Ys[(k4 * 4 + kk) * 128 + col];
#pragma unroll
      for (int q = 0; q < 4; q++) acc[q] += xv[q][kk] * yv;
    }
  }
#pragma unroll
  for (int q = 0; q < 4; q++) {
    int row = rbase + q;
    C[row * 128 + col] = acc[q];
    short bv = f2bf(acc[q]);
    if (tableId == 1) {
      if (e <= 63) {
        P1[row * 8192 + (63 - e) * 128 + col] = bv;
        P1t[((63 - e) * 128 + col) * 128 + row] = bv;
      } else if (e == 64) {
        Bpow[16384 + row * 128 + col] = acc[q];   // Bpow[1] = A^64
        P2t[(62 * 128 + col) * 128 + row] = bv;   // (A^64)^1
      }
    } else {
      if (e <= 63)
        P2t[((63 - e) * 128 + col) * 128 + row] = bv;
    }
  }
}

// ---------- build shifted/masked inputs for chunk-combine + tail ----------
// Vsh[k][b]: V_{b,c} right-aligned so a single GEMM vs P2 applies (A^64)^{F-1-c}
// TlX[k][b]: tail x_t right-aligned so a single GEMM vs P1 applies A^{r-1-u}
__global__ void build_shift(const float* __restrict__ V, const short* __restrict__ seqs,
                            const int* __restrict__ seq_lens,
                            short* __restrict__ Vsh, short* __restrict__ TlX)
{
  int idx = blockIdx.x * 256 + threadIdx.x;   // 0..131071
  int pp = idx >> 16;
  int e = idx & 65535;
  int k = e >> 3, b = e & 7;
  int cp = k >> 7, i = k & 127;
  int L = seq_lens[b];
  short v = 0;
  if (pp == 0) {
    int F = L >> 6;
    int sh = 64 - F;
    if (cp >= sh) v = f2bf(V[(size_t)(b * 64 + (cp - sh)) * 128 + i]);
    Vsh[e] = v;
  } else {
    int F = L >> 6, rr = L & 63;
    int sh = 64 - rr;
    if (cp >= sh) v = seqs[((size_t)b * 4096 + F * 64 + (cp - sh)) * 128 + i];
    TlX[e] = v;
  }
}

// ---------- tiny split-K GEMMs: h_F = Vsh x P2, tailsum = TlX x P1 ----------
__global__ __launch_bounds__(256) void tiny_gemm(
    const short* __restrict__ Vsh, const short* __restrict__ TlX,
    const short* __restrict__ P2t, const short* __restrict__ P1t,
    float* __restrict__ hFtail)
{
  int pp = blockIdx.x >> 4, ks = blockIdx.x & 15;
  const short* X = pp ? TlX : Vsh;     // [8192][8] bf16
  const short* P = pp ? P1t : P2t;     // [8192][128] bf16
  float* outp = hFtail + pp * 1024;    // [8][128]
  int i = threadIdx.x & 127, g = threadIdx.x >> 7;
  float acc[4] = {0, 0, 0, 0};
  for (int k = ks * 512; k < ks * 512 + 512; ++k) {
    float pv = bf2f(P[k * 128 + i]);
    short4v xv = *(const short4v*)(X + k * 8 + g * 4);
#pragma unroll
    for (int q = 0; q < 4; q++) acc[q] += bf2f(xv[q]) * pv;
  }
#pragma unroll
  for (int q = 0; q < 4; q++) atomicAdd(&outp[(g * 4 + q) * 128 + i], acc[q]);
}

// ---------- h_final = A^{r_b} h_F + tailsum ; store transposed bf16 for decoder ----------
__global__ __launch_bounds__(256) void final_combine(
    const float* __restrict__ hFtail, const float* __restrict__ Apow,
    const int* __restrict__ seq_lens, short* __restrict__ Xt0)
{
  int i = threadIdx.x & 127, half = threadIdx.x >> 7;
#pragma unroll
  for (int q = 0; q < 4; q++) {
    int b = half * 4 + q;
    int L = seq_lens[b];
    int rr = L & 63;
    const float* M = Apow + (size_t)rr * 16384;
    const float* hF = hFtail + b * 128;
    const float* ts = hFtail + 1024 + b * 128;
    float a = ts[i];
    for (int j = 0; j < 128; j++) a += M[i * 128 + j] * hF[j];
    Xt0[i * 8 + b] = f2bf(a);
  }
}

// ---------- batch-8 matvec: out[b][n] = sum_k Xt[k][b] * W[k][n] (+bias,+gelu,+residual) ----------
__global__ __launch_bounds__(256) void matvec8(
    const short* __restrict__ Xt, const float* __restrict__ W,
    const float* __restrict__ bias, int K, int N,
    float* __restrict__ outF, short* __restrict__ outT,
    const float* __restrict__ resid, int doGelu)
{
  __shared__ float red[4][64][8];
  int tid = threadIdx.x;
  int c = tid & 63, sl = tid >> 6;
  int n = blockIdx.x * 64 + c;
  int kPer = K >> 2;
  float acc[8] = {0, 0, 0, 0, 0, 0, 0, 0};
  for (int k = sl * kPer; k < (sl + 1) * kPer; ++k) {
    short8 xv = *(const short8*)(Xt + k * 8);     // broadcast 16B (all 8 batches)
    float wv = W[(size_t)k * N + n];              // coalesced
#pragma unroll
    for (int b = 0; b < 8; b++) acc[b] += bf2f(xv[b]) * wv;
  }
#pragma unroll
  for (int b = 0; b < 8; b++) red[sl][c][b] = acc[b];
  __syncthreads();
  if (sl == 0) {
#pragma unroll
    for (int s = 1; s < 4; s++)
#pragma unroll
      for (int b = 0; b < 8; b++) acc[b] += red[s][c][b];
    float bn = bias ? bias[n] : 0.0f;
#pragma unroll
    for (int b = 0; b < 8; b++) {
      float v = acc[b] + bn;
      if (doGelu) v = gelu_f(v);
      if (resid) v += resid[(size_t)b * N + n];
      if (outF) outF[(size_t)b * N + n] = v;
      if (outT) outT[n * 8 + b] = f2bf(v);
    }
  }
}

// ---------- LayerNorm over N=1024, write transposed bf16 [n][b] ----------
__global__ __launch_bounds__(256) void ln8(const float* __restrict__ in,
                                           const float* __restrict__ g,
                                           const float* __restrict__ bb,
                                           short* __restrict__ outT)
{
  int row = blockIdx.x;
  const float* xr = in + row * 1024;
  int tid = threadIdx.x;
  float4v v = ((const float4v*)xr)[tid];
  float s1 = v[0] + v[1] + v[2] + v[3];
  float s2 = v[0] * v[0] + v[1] * v[1] + v[2] * v[2] + v[3] * v[3];
  for (int o = 32; o > 0; o >>= 1) {
    s1 += __shfl_down(s1, o, 64);
    s2 += __shfl_down(s2, o, 64);
  }
  __shared__ float ws[2][4];
  int wave = tid >> 6, lane = tid & 63;
  if (lane == 0) { ws[0][wave] = s1; ws[1][wave] = s2; }
  __syncthreads();
  s1 = ws[0][0] + ws[0][1] + ws[0][2] + ws[0][3];
  s2 = ws[1][0] + ws[1][1] + ws[1][2] + ws[1][3];
  float mu = s1 * (1.0f / 1024.0f);
  float var = s2 * (1.0f / 1024.0f) - mu * mu;
  float rs = rsqrtf(var + 1e-5f);
#pragma unroll
  for (int j = 0; j < 4; j++) {
    int n = tid * 4 + j;
    float val = (v[j] - mu) * rs * g[n] + bb[n];
    outT[n * 8 + row] = f2bf(val);
  }
}

// ---------- host ----------
extern "C" void kernel_launch(void* const* d_in, const int* in_sizes, int n_in,
                              void* d_out, int out_size, void* d_ws, size_t ws_size,
                              hipStream_t stream)
{
  (void)in_sizes; (void)n_in; (void)out_size; (void)ws_size;
  const float* x      = (const float*)d_in[0];
  const int* seq_lens = (const int*)d_in[1];
  const float* A      = (const float*)d_in[2];
  const float* enc_w1 = (const float*)d_in[3];
  const float* enc_b1 = (const float*)d_in[4];
  const float* enc_w2 = (const float*)d_in[5];
  const float* enc_b2 = (const float*)d_in[6];
  const float* proj_w = (const float*)d_in[7];
  const float* proj_b = (const float*)d_in[8];
  const float* ln1_g  = (const float*)d_in[9];
  const float* ln1_b  = (const float*)d_in[10];
  const float* ffn_w1 = (const float*)d_in[11];
  const float* ffn_b1 = (const float*)d_in[12];
  const float* ffn_w2 = (const float*)d_in[13];
  const float* ffn_b2 = (const float*)d_in[14];
  const float* ln2_g  = (const float*)d_in[15];
  const float* ln2_b  = (const float*)d_in[16];
  const float* out_w  = (const float*)d_in[17];
  const float* out_b  = (const float*)d_in[18];

  char* p = (char*)d_ws;
  auto alloc = [&](size_t bytes) { char* r = p; p += (bytes + 255) & ~(size_t)255; return r; };
  short* h_mid = (short*)alloc(32768ull * 1024 * 2);  // encoder mid, bf16
  short* seqs  = (short*)alloc(32768ull * 128 * 2);   // Bx_t, bf16
  short* w1T   = (short*)alloc(1024ull * 384 * 2);
  short* w2T   = (short*)alloc(128ull * 1024 * 2);
  float* Apow  = (float*)alloc(65ull * 16384 * 4);    // A^0..A^64 fp32
  float* Bpow  = (float*)alloc(65ull * 16384 * 4);    // (A^64)^0..^64 fp32
  short* P1    = (short*)alloc(128ull * 8192 * 2);    // [n][(63-j)*128+i] = A^j, bf16
  short* P1t   = (short*)alloc(8192ull * 128 * 2);
  short* P2t   = (short*)alloc(8192ull * 128 * 2);
  float* V     = (float*)alloc(512ull * 128 * 4);     // chunk values (atomic, zeroed)
  float* hFtail= (float*)alloc(2ull * 8 * 128 * 4);   // [h_F | tailsum] (atomic, zeroed)
  short* Vsh   = (short*)alloc(8192ull * 8 * 2);
  short* TlX   = (short*)alloc(8192ull * 8 * 2);
  short* Xt0   = (short*)alloc(128ull * 8 * 2);
  float* projected = (float*)alloc(8ull * 1024 * 4);
  short* nh_t  = (short*)alloc(1024ull * 8 * 2);
  short* f_t   = (short*)alloc(512ull * 8 * 2);
  float* ffn_out = (float*)alloc(8ull * 1024 * 4);
  short* y_t   = (short*)alloc(1024ull * 8 * 2);

  // V and hFtail are adjacent (V size is 256-aligned): one memset
  hipMemsetAsync(V, 0, 512ull * 128 * 4 + 2ull * 8 * 128 * 4, stream);

  prep_kernel<<<2176, 256, 0, stream>>>(enc_w1, enc_w2, A, w1T, w2T, Apow, Bpow, P1, P1t, P2t);
  for (int m = 1; m <= 32; m <<= 1)
    power_round<<<m * 16, 256, 0, stream>>>(Apow, m, 1, Bpow, P1, P1t, P2t);
  for (int m = 1; m <= 32; m <<= 1)
    power_round<<<m * 16, 256, 0, stream>>>(Bpow, m, 2, Bpow, P1, P1t, P2t);

  // encoder
  gemm_bt<1, 0><<<dim3(8, 256, 1), 256, 0, stream>>>(x, w1T, enc_b1, h_mid,
      384, 384, 1024, 12, 0, seq_lens, 1);
  gemm_bt<0, 1><<<dim3(1, 256, 1), 256, 0, stream>>>(h_mid, w2T, enc_b2, seqs,
      1024, 1024, 128, 32, 0, seq_lens, 1);

  // recurrence as GEMMs: per-chunk values, shifted combine, tail
  gemm_bt<0, 2><<<dim3(1, 4, 16), 256, 0, stream>>>(seqs, P1, nullptr, V,
      8192, 8192, 128, 16, 512, seq_lens, 0);
  build_shift<<<512, 256, 0, stream>>>(V, seqs, seq_lens, Vsh, TlX);
  tiny_gemm<<<32, 256, 0, stream>>>(Vsh, TlX, P2t, P1t, hFtail);
  final_combine<<<1, 256, 0, stream>>>(hFtail, Apow, seq_lens, Xt0);

  // decoder
  matvec8<<<16, 256, 0, stream>>>(Xt0, proj_w, proj_b, 128, 1024, projected, nullptr, nullptr, 0);
  ln8<<<8, 256, 0, stream>>>(projected, ln1_g, ln1_b, nh_t);
  matvec8<<<8, 256, 0, stream>>>(nh_t, ffn_w1, ffn_b1, 1024, 512, nullptr, f_t, nullptr, 1);
  matvec8<<<16, 256, 0, stream>>>(f_t, ffn_w2, ffn_b2, 512, 1024, ffn_out, nullptr, projected, 0);
  ln8<<<8, 256, 0, stream>>>(ffn_out, ln2_g, ln2_b, y_t);
  matvec8<<<16, 256, 0, stream>>>(y_t, out_w, out_b, 1024, 1024, (float*)d_out, nullptr, nullptr, 0);
}

// Round 2
// 450.014 us; speedup vs baseline: 1.6107x; 1.6107x over previous
//
#include <hip/hip_runtime.h>

// ---------- types ----------
typedef __attribute__((ext_vector_type(8))) short short8;   // 8 bf16 (4 VGPR)
typedef __attribute__((ext_vector_type(4))) short short4v;  // 4 bf16
typedef __attribute__((ext_vector_type(4))) float float4v;  // 4 fp32

__device__ __forceinline__ float bf2f(short s) {
  union { float f; unsigned u; } cv; cv.u = ((unsigned)(unsigned short)s) << 16; return cv.f;
}
__device__ __forceinline__ short f2bf(float f) {   // RNE fp32->bf16, inputs never NaN
  union { float f; unsigned u; } cv; cv.f = f;
  unsigned u = cv.u;
  unsigned r = u + 0x7FFFu + ((u >> 16) & 1u);
  return (short)(r >> 16);
}
__device__ __forceinline__ float gelu_f(float v) {
  return 0.5f * v * (1.0f + erff(v * 0.70710678118654752440f));
}

// ---------- MFMA GEMM: C[m][n] = sum_k A[m][k] * BT[n][k]  (128x128 tile, BK=32) ----------
// A_FP32: A is fp32 (converted to bf16 while staging); else A is bf16.
// EPI: 0 = +bias, gelu, store bf16 ; 1 = +bias, store bf16 ; 2 = atomicAdd fp32 (split-K)
template<int A_FP32, int EPI>
__global__ __launch_bounds__(256) void gemm_bt(
    const void* __restrict__ A_, const short* __restrict__ BT,
    const float* __restrict__ bias, void* __restrict__ out,
    int lda, int ldb, int ldc, int kSteps, int kChunk,
    const int* __restrict__ seq_lens, int seqSkip)
{
  int m0 = blockIdx.y * 128;
  int n0 = blockIdx.x * 128;
  if (seqSkip) {               // rows are (b*4096 + t); skip tiles fully past seq_len
    int b = m0 >> 12, t = m0 & 4095;
    if (t >= seq_lens[b]) return;
  }
  int kBase = blockIdx.z * kChunk;

  __shared__ short As[128 * 32];
  __shared__ short Bs[128 * 32];

  int tid = threadIdx.x;
  int lane = tid & 63, wave = tid >> 6;
  int l15 = lane & 15, quad = lane >> 4;
  int wm = wave & 1, wn = wave >> 1;   // wave quadrant (64x64)

  float4v acc[4][4];
#pragma unroll
  for (int i = 0; i < 4; i++)
#pragma unroll
    for (int j = 0; j < 4; j++) acc[i][j] = 0;

  int r = tid >> 1;            // tile row handled by this thread for staging
  int off = (tid & 1) * 16;    // 16-element half of the 32-wide k slice

  for (int ks = 0; ks < kSteps; ++ks) {
    int kk = kBase + ks * 32;
    if (A_FP32) {
      const float* Af = (const float*)A_ + (size_t)(m0 + r) * lda + kk + off;
      float4v x0 = ((const float4v*)Af)[0];
      float4v x1 = ((const float4v*)Af)[1];
      float4v x2 = ((const float4v*)Af)[2];
      float4v x3 = ((const float4v*)Af)[3];
      short tmp[16];
#pragma unroll
      for (int j = 0; j < 4; j++) {
        tmp[j] = f2bf(x0[j]); tmp[4 + j] = f2bf(x1[j]);
        tmp[8 + j] = f2bf(x2[j]); tmp[12 + j] = f2bf(x3[j]);
      }
      *(short8*)&As[r * 32 + off] = *(short8*)tmp;
      *(short8*)&As[r * 32 + off + 8] = *(short8*)(tmp + 8);
    } else {
      const short* Ab = (const short*)A_ + (size_t)(m0 + r) * lda + kk + off;
      *(short8*)&As[r * 32 + off]     = ((const short8*)Ab)[0];
      *(short8*)&As[r * 32 + off + 8] = ((const short8*)Ab)[1];
    }
    {
      const short* Bb = BT + (size_t)(n0 + r) * ldb + kk + off;
      *(short8*)&Bs[r * 32 + off]     = ((const short8*)Bb)[0];
      *(short8*)&Bs[r * 32 + off + 8] = ((const short8*)Bb)[1];
    }
    __syncthreads();
    short8 af[4], bfr[4];
#pragma unroll
    for (int im = 0; im < 4; im++)
      af[im] = *(short8*)&As[(wm * 64 + im * 16 + l15) * 32 + quad * 8];
#pragma unroll
    for (int in = 0; in < 4; in++)
      bfr[in] = *(short8*)&Bs[(wn * 64 + in * 16 + l15) * 32 + quad * 8];
#pragma unroll
    for (int im = 0; im < 4; im++)
#pragma unroll
      for (int in = 0; in < 4; in++)
        acc[im][in] = __builtin_amdgcn_mfma_f32_16x16x32_bf16(af[im], bfr[in], acc[im][in], 0, 0, 0);
    __syncthreads();
  }

  // C/D layout: col = lane&15, row = quad*4 + reg
#pragma unroll
  for (int im = 0; im < 4; im++) {
#pragma unroll
    for (int in = 0; in < 4; in++) {
      int n = n0 + wn * 64 + in * 16 + l15;
#pragma unroll
      for (int reg = 0; reg < 4; reg++) {
        int m = m0 + wm * 64 + im * 16 + quad * 4 + reg;
        float v = acc[im][in][reg];
        if (EPI == 0) {
          v += bias[n]; v = gelu_f(v);
          ((short*)out)[(size_t)m * ldc + n] = f2bf(v);
        } else if (EPI == 1) {
          v += bias[n];
          ((short*)out)[(size_t)m * ldc + n] = f2bf(v);
        } else {
          atomicAdd((float*)out + (size_t)m * ldc + n, v);
        }
      }
    }
  }
}

// ---------- prep: all weight conversions + identity/A seeds ----------
// ranges: w1T(393216) w2T(131072) projB(131072) ffn1B(524288) ffn2B(524288)
//         outB(1048576) identity+A(16384)
__global__ void prep_wide(const float* __restrict__ w1, const float* __restrict__ w2,
                          const float* __restrict__ proj_w, const float* __restrict__ ffn_w1,
                          const float* __restrict__ ffn_w2, const float* __restrict__ out_w,
                          const float* __restrict__ A,
                          short* __restrict__ w1T, short* __restrict__ w2T,
                          short* __restrict__ projB, short* __restrict__ ffn1B,
                          short* __restrict__ ffn2B, short* __restrict__ outB,
                          short* __restrict__ P1, short* __restrict__ P1t,
                          short* __restrict__ P2t,
                          short* __restrict__ Spow, short* __restrict__ SpowT)
{
  int idx = blockIdx.x * 256 + threadIdx.x;
  if (idx < 393216) {                        // w1T[n][k] = w1[k][n]
    int n = idx / 384, k = idx % 384;
    w1T[idx] = f2bf(w1[k * 1024 + n]);
    return;
  }
  idx -= 393216;
  if (idx < 131072) {                        // w2T[n][k] = w2[k][n]
    int n = idx / 1024, k = idx % 1024;
    w2T[idx] = f2bf(w2[k * 128 + n]);
    return;
  }
  idx -= 131072;
  if (idx < 131072) { projB[idx] = f2bf(proj_w[idx]); return; }
  idx -= 131072;
  if (idx < 524288) { ffn1B[idx] = f2bf(ffn_w1[idx]); return; }
  idx -= 524288;
  if (idx < 524288) { ffn2B[idx] = f2bf(ffn_w2[idx]); return; }
  idx -= 524288;
  if (idx < 1048576) { outB[idx] = f2bf(out_w[idx]); return; }
  idx -= 1048576;
  if (idx < 16384) {                         // identity slots (e=0) + A seed
    int i = idx >> 7, j = idx & 127;
    short bidv = f2bf((i == j) ? 1.0f : 0.0f);
    P1[i * 8192 + 63 * 128 + j] = bidv;
    P1t[(63 * 128 + j) * 128 + i] = bidv;
    P2t[(63 * 128 + j) * 128 + i] = bidv;
    short ab = f2bf(A[idx]);
    Spow[idx] = ab;                          // A^1 row-major
    SpowT[(size_t)j * 128 + i] = ab;         // transposed
  }
}

// ---------- single-block MFMA squaring chain ----------
// Spow[k]: k=0..6 -> A^(2^k) (A^1..A^64); k=7..11 -> M^(2^(k-6)) with M=A^64.
// Each step squares the previous: Spow[s] = Spow[s-1]^2. 11 sequential 128^3 matmuls.
__global__ __launch_bounds__(256) void pow_chain(short* __restrict__ Spow,
                                                 short* __restrict__ SpowT)
{
  __shared__ short X[16384];    // cur, row-major
  __shared__ short XT[16384];   // cur, transposed
  int t = threadIdx.x;
  for (int i = t * 8; i < 16384; i += 2048) {
    *(short8*)&X[i]  = *(const short8*)&Spow[i];
    *(short8*)&XT[i] = *(const short8*)&SpowT[i];
  }
  __syncthreads();
  int lane = t & 63, wave = t >> 6, l15 = lane & 15, quad = lane >> 4;
  for (int step = 1; step <= 11; ++step) {
    short8 af[2][4], bfr[8][4];
#pragma unroll
    for (int mt = 0; mt < 2; mt++)
#pragma unroll
      for (int ks = 0; ks < 4; ks++)
        af[mt][ks] = *(short8*)&X[(wave * 32 + mt * 16 + l15) * 128 + ks * 32 + quad * 8];
#pragma unroll
    for (int nt = 0; nt < 8; nt++)
#pragma unroll
      for (int ks = 0; ks < 4; ks++)
        bfr[nt][ks] = *(short8*)&XT[(nt * 16 + l15) * 128 + ks * 32 + quad * 8];
    __syncthreads();                       // all frag loads done before in-place overwrite
    float4v acc[2][8];
#pragma unroll
    for (int mt = 0; mt < 2; mt++)
#pragma unroll
      for (int nt = 0; nt < 8; nt++) acc[mt][nt] = 0;
#pragma unroll
    for (int ks = 0; ks < 4; ks++)
#pragma unroll
      for (int mt = 0; mt < 2; mt++)
#pragma unroll
        for (int nt = 0; nt < 8; nt++)
          acc[mt][nt] = __builtin_amdgcn_mfma_f32_16x16x32_bf16(af[mt][ks], bfr[nt][ks], acc[mt][nt], 0, 0, 0);
    short* gX  = Spow  + (size_t)step * 16384;
    short* gXT = SpowT + (size_t)step * 16384;
#pragma unroll
    for (int mt = 0; mt < 2; mt++)
#pragma unroll
      for (int nt = 0; nt < 8; nt++)
#pragma unroll
        for (int reg = 0; reg < 4; reg++) {
          int m = wave * 32 + mt * 16 + quad * 4 + reg;
          int n = nt * 16 + l15;
          short v = f2bf(acc[mt][nt][reg]);
          X[m * 128 + n] = v; XT[n * 128 + m] = v;
          gX[m * 128 + n] = v; gXT[n * 128 + m] = v;
        }
    __syncthreads();
  }
}

// ---------- wide fill: block computes one table slot via seed-product chain ----------
// bid 0..62: table1 (A^e, e=bid+1) -> P1 + P1t slot 63-e
// bid 63..125: table2 ((A^64)^e, e=bid-62) -> P2t slot 63-e
__global__ __launch_bounds__(256) void pow_fill(const short* __restrict__ Spow,
                                                const short* __restrict__ SpowT,
                                                short* __restrict__ P1,
                                                short* __restrict__ P1t,
                                                short* __restrict__ P2t)
{
  __shared__ short cur[16384];
  __shared__ short Bt[16384];
  int bid = blockIdx.x;
  int table1 = bid < 63;
  int e = table1 ? bid + 1 : bid - 62;
  int t = threadIdx.x;
  int lane = t & 63, wave = t >> 6, l15 = lane & 15, quad = lane >> 4;

  int bits = e;
  int k0 = __ffs(bits) - 1; bits &= bits - 1;
  int s0 = table1 ? k0 : (k0 == 0 ? 6 : 6 + k0);
  for (int i = t * 8; i < 16384; i += 2048)
    *(short8*)&cur[i] = *(const short8*)&Spow[(size_t)s0 * 16384 + i];

  while (bits) {
    int k = __ffs(bits) - 1; bits &= bits - 1;
    int si = table1 ? k : (k == 0 ? 6 : 6 + k);
    for (int i = t * 8; i < 16384; i += 2048)
      *(short8*)&Bt[i] = *(const short8*)&SpowT[(size_t)si * 16384 + i];
    __syncthreads();
    short8 af[2][4], bfr[8][4];
#pragma unroll
    for (int mt = 0; mt < 2; mt++)
#pragma unroll
      for (int ks = 0; ks < 4; ks++)
        af[mt][ks] = *(short8*)&cur[(wave * 32 + mt * 16 + l15) * 128 + ks * 32 + quad * 8];
#pragma unroll
    for (int nt = 0; nt < 8; nt++)
#pragma unroll
      for (int ks = 0; ks < 4; ks++)
        bfr[nt][ks] = *(short8*)&Bt[(nt * 16 + l15) * 128 + ks * 32 + quad * 8];
    __syncthreads();                       // loads done before in-place write of cur
    float4v acc[2][8];
#pragma unroll
    for (int mt = 0; mt < 2; mt++)
#pragma unroll
      for (int nt = 0; nt < 8; nt++) acc[mt][nt] = 0;
#pragma unroll
    for (int ks = 0; ks < 4; ks++)
#pragma unroll
      for (int mt = 0; mt < 2; mt++)
#pragma unroll
        for (int nt = 0; nt < 8; nt++)
          acc[mt][nt] = __builtin_amdgcn_mfma_f32_16x16x32_bf16(af[mt][ks], bfr[nt][ks], acc[mt][nt], 0, 0, 0);
#pragma unroll
    for (int mt = 0; mt < 2; mt++)
#pragma unroll
      for (int nt = 0; nt < 8; nt++)
#pragma unroll
        for (int reg = 0; reg < 4; reg++) {
          int m = wave * 32 + mt * 16 + quad * 4 + reg;
          int n = nt * 16 + l15;
          cur[m * 128 + n] = f2bf(acc[mt][nt][reg]);
        }
    __syncthreads();
  }
  __syncthreads();
  int slot = 63 - e;
  for (int idx = t; idx < 16384; idx += 256) {
    int i = idx >> 7, j = idx & 127;
    short v = cur[idx];
    if (table1) {
      P1[i * 8192 + slot * 128 + j] = v;
      P1t[(slot * 128 + j) * 128 + i] = v;
    } else {
      P2t[(slot * 128 + j) * 128 + i] = v;
    }
  }
}

// ---------- build shifted/masked inputs for chunk-combine + tail (unchanged math) ----------
__global__ void build_shift(const float* __restrict__ V, const short* __restrict__ seqs,
                            const int* __restrict__ seq_lens,
                            short* __restrict__ Vsh, short* __restrict__ TlX)
{
  int idx = blockIdx.x * 256 + threadIdx.x;   // 0..131071
  int pp = idx >> 16;
  int e = idx & 65535;
  int k = e >> 3, b = e & 7;
  int cp = k >> 7, i = k & 127;
  int L = seq_lens[b];
  short v = 0;
  if (pp == 0) {
    int F = L >> 6;
    int sh = 64 - F;
    if (cp >= sh) v = f2bf(V[(size_t)(b * 64 + (cp - sh)) * 128 + i]);
    Vsh[e] = v;
  } else {
    int F = L >> 6, rr = L & 63;
    int sh = 64 - rr;
    if (cp >= sh) v = seqs[((size_t)b * 4096 + F * 64 + (cp - sh)) * 128 + i];
    TlX[e] = v;
  }
}

// ---------- tiny split-K GEMMs: h_F = Vsh x P2, tailsum = TlX x P1 (unchanged) ----------
__global__ __launch_bounds__(256) void tiny_gemm(
    const short* __restrict__ Vsh, const short* __restrict__ TlX,
    const short* __restrict__ P2t, const short* __restrict__ P1t,
    float* __restrict__ hFtail)
{
  int pp = blockIdx.x >> 4, ks = blockIdx.x & 15;
  const short* X = pp ? TlX : Vsh;     // [8192][8] bf16
  const short* P = pp ? P1t : P2t;     // [8192][128] bf16
  float* outp = hFtail + pp * 1024;    // [8][128]
  int i = threadIdx.x & 127, g = threadIdx.x >> 7;
  float acc[4] = {0, 0, 0, 0};
  for (int k = ks * 512; k < ks * 512 + 512; ++k) {
    float pv = bf2f(P[k * 128 + i]);
    short4v xv = *(const short4v*)(X + k * 8 + g * 4);
#pragma unroll
    for (int q = 0; q < 4; q++) acc[q] += bf2f(xv[q]) * pv;
  }
#pragma unroll
  for (int q = 0; q < 4; q++) atomicAdd(&outp[(g * 4 + q) * 128 + i], acc[q]);
}

// ---------- decoder stage 1: h = A^rr hF + tail (recomputed per block), proj matvec ----------
__global__ __launch_bounds__(256) void proj_stage(
    const float* __restrict__ hFtail, const short* __restrict__ P1t,
    const int* __restrict__ seq_lens, const short* __restrict__ projB,
    const float* __restrict__ proj_b, float* __restrict__ projected)
{
  __shared__ short hT[128 * 8];        // bf16 [k][b]
  __shared__ float red[4][64][8];
  int t = threadIdx.x;
  {
    int b = t >> 5, i4 = (t & 31) * 4;
    int rr = seq_lens[b] & 63;
    const short* M = P1t + (size_t)(63 - rr) * 128 * 128;   // (A^rr)[i][j] = M[j*128+i]
    const float* hF = hFtail + b * 128;
    float acc[4];
#pragma unroll
    for (int q = 0; q < 4; q++) acc[q] = hFtail[1024 + b * 128 + i4 + q];  // tail
    for (int j = 0; j < 128; ++j) {
      float hv = hF[j];
      short4v mv = *(const short4v*)&M[j * 128 + i4];
#pragma unroll
      for (int q = 0; q < 4; q++) acc[q] += bf2f(mv[q]) * hv;
    }
#pragma unroll
    for (int q = 0; q < 4; q++) hT[(i4 + q) * 8 + b] = f2bf(acc[q]);
  }
  __syncthreads();
  int c = t & 63, sl = t >> 6;
  int n = blockIdx.x * 64 + c;
  float acc[8] = {0, 0, 0, 0, 0, 0, 0, 0};
  for (int k = sl * 32; k < sl * 32 + 32; ++k) {
    short8 xv = *(short8*)&hT[k * 8];
    float wv = bf2f(projB[k * 1024 + n]);
#pragma unroll
    for (int b = 0; b < 8; b++) acc[b] += bf2f(xv[b]) * wv;
  }
#pragma unroll
  for (int b = 0; b < 8; b++) red[sl][c][b] = acc[b];
  __syncthreads();
  if (sl == 0) {
#pragma unroll
    for (int s = 1; s < 4; s++)
#pragma unroll
      for (int b = 0; b < 8; b++) acc[b] += red[s][c][b];
    float bn = proj_b[n];
#pragma unroll
    for (int b = 0; b < 8; b++) projected[b * 1024 + n] = acc[b] + bn;
  }
}

// ---------- decoder stage 2: LN1(projected) @ ffn_w1 -> ffn1raw (split-K atomics) ----------
__global__ __launch_bounds__(256) void ffn1_stage(
    const float* __restrict__ projected, const float* __restrict__ g1,
    const float* __restrict__ b1, const short* __restrict__ ffn1B,
    float* __restrict__ ffn1raw)
{
  __shared__ float part[8][32][2];
  __shared__ float stats[8][2];
  __shared__ short xT[256 * 8];
  __shared__ float red[4][64][8];
  int t = threadIdx.x;
  { int b = t >> 5, j0 = t & 31; float s = 0, q = 0;
    for (int k = j0 * 32; k < j0 * 32 + 32; ++k) { float v = projected[b * 1024 + k]; s += v; q += v * v; }
    part[b][j0][0] = s; part[b][j0][1] = q; }
  __syncthreads();
  if (t < 8) {
    float s = 0, q = 0;
    for (int j = 0; j < 32; j++) { s += part[t][j][0]; q += part[t][j][1]; }
    float mu = s * (1.0f / 1024.0f);
    float var = q * (1.0f / 1024.0f) - mu * mu;
    stats[t][0] = mu; stats[t][1] = rsqrtf(var + 1e-5f);
  }
  __syncthreads();
  int ky0 = blockIdx.y * 256;
  for (int idx = t; idx < 2048; idx += 256) {
    int kl = idx >> 3, b = idx & 7; int k = ky0 + kl;
    float v = (projected[b * 1024 + k] - stats[b][0]) * stats[b][1] * g1[k] + b1[k];
    xT[kl * 8 + b] = f2bf(v);
  }
  __syncthreads();
  int c = t & 63, sl = t >> 6;
  int n = blockIdx.x * 64 + c;
  float acc[8] = {0, 0, 0, 0, 0, 0, 0, 0};
  for (int kl = sl * 64; kl < sl * 64 + 64; ++kl) {
    short8 xv = *(short8*)&xT[kl * 8];
    float wv = bf2f(ffn1B[(size_t)(ky0 + kl) * 512 + n]);
#pragma unroll
    for (int b = 0; b < 8; b++) acc[b] += bf2f(xv[b]) * wv;
  }
#pragma unroll
  for (int b = 0; b < 8; b++) red[sl][c][b] = acc[b];
  __syncthreads();
  if (sl == 0) {
#pragma unroll
    for (int s = 1; s < 4; s++)
#pragma unroll
      for (int b = 0; b < 8; b++) acc[b] += red[s][c][b];
#pragma unroll
    for (int b = 0; b < 8; b++) atomicAdd(&ffn1raw[b * 512 + n], acc[b]);
  }
}

// ---------- decoder stage 3: gelu(ffn1raw + b1) @ ffn_w2 -> ffn2raw ----------
__global__ __launch_bounds__(256) void ffn2_stage(
    const float* __restrict__ ffn1raw, const float* __restrict__ fb1,
    const short* __restrict__ ffn2B, float* __restrict__ ffn2raw)
{
  __shared__ short xT[256 * 8];
  __shared__ float red[4][64][8];
  int t = threadIdx.x;
  int ky0 = blockIdx.y * 256;
  for (int idx = t; idx < 2048; idx += 256) {
    int kl = idx >> 3, b = idx & 7; int k = ky0 + kl;
    float v = gelu_f(ffn1raw[b * 512 + k] + fb1[k]);
    xT[kl * 8 + b] = f2bf(v);
  }
  __syncthreads();
  int c = t & 63, sl = t >> 6;
  int n = blockIdx.x * 64 + c;
  float acc[8] = {0, 0, 0, 0, 0, 0, 0, 0};
  for (int kl = sl * 64; kl < sl * 64 + 64; ++kl) {
    short8 xv = *(short8*)&xT[kl * 8];
    float wv = bf2f(ffn2B[(size_t)(ky0 + kl) * 1024 + n]);
#pragma unroll
    for (int b = 0; b < 8; b++) acc[b] += bf2f(xv[b]) * wv;
  }
#pragma unroll
  for (int b = 0; b < 8; b++) red[sl][c][b] = acc[b];
  __syncthreads();
  if (sl == 0) {
#pragma unroll
    for (int s = 1; s < 4; s++)
#pragma unroll
      for (int b = 0; b < 8; b++) acc[b] += red[s][c][b];
#pragma unroll
    for (int b = 0; b < 8; b++) atomicAdd(&ffn2raw[b * 1024 + n], acc[b]);
  }
}

// ---------- decoder stage 4: LN2(ffn2raw + b2 + projected) @ out_w + out_b -> d_out ----------
__global__ __launch_bounds__(256) void out_stage(
    const float* __restrict__ ffn2raw, const float* __restrict__ fb2,
    const float* __restrict__ projected, const float* __restrict__ g2,
    const float* __restrict__ b2ln, const short* __restrict__ outB,
    const float* __restrict__ out_b, float* __restrict__ d_out)
{
  __shared__ float part[8][32][2];
  __shared__ float stats[8][2];
  __shared__ short xT[512 * 8];
  __shared__ float red[4][64][8];
  int t = threadIdx.x;
  { int b = t >> 5, j0 = t & 31; float s = 0, q = 0;
    for (int k = j0 * 32; k < j0 * 32 + 32; ++k) {
      float v = ffn2raw[b * 1024 + k] + fb2[k] + projected[b * 1024 + k];
      s += v; q += v * v;
    }
    part[b][j0][0] = s; part[b][j0][1] = q; }
  __syncthreads();
  if (t < 8) {
    float s = 0, q = 0;
    for (int j = 0; j < 32; j++) { s += part[t][j][0]; q += part[t][j][1]; }
    float mu = s * (1.0f / 1024.0f);
    float var = q * (1.0f / 1024.0f) - mu * mu;
    stats[t][0] = mu; stats[t][1] = rsqrtf(var + 1e-5f);
  }
  __syncthreads();
  int ky0 = blockIdx.y * 512;
  for (int idx = t; idx < 4096; idx += 256) {
    int kl = idx >> 3, b = idx & 7; int k = ky0 + kl;
    float v = ffn2raw[b * 1024 + k] + fb2[k] + projected[b * 1024 + k];
    v = (v - stats[b][0]) * stats[b][1] * g2[k] + b2ln[k];
    xT[kl * 8 + b] = f2bf(v);
  }
  __syncthreads();
  int c = t & 63, sl = t >> 6;
  int n = blockIdx.x * 64 + c;
  float acc[8] = {0, 0, 0, 0, 0, 0, 0, 0};
  for (int kl = sl * 128; kl < sl * 128 + 128; ++kl) {
    short8 xv = *(short8*)&xT[kl * 8];
    float wv = bf2f(outB[(size_t)(ky0 + kl) * 1024 + n]);
#pragma unroll
    for (int b = 0; b < 8; b++) acc[b] += bf2f(xv[b]) * wv;
  }
#pragma unroll
  for (int b = 0; b < 8; b++) red[sl][c][b] = acc[b];
  __syncthreads();
  if (sl == 0) {
#pragma unroll
    for (int s = 1; s < 4; s++)
#pragma unroll
      for (int b = 0; b < 8; b++) acc[b] += red[s][c][b];
    float bn = (blockIdx.y == 0) ? out_b[n] : 0.0f;
#pragma unroll
    for (int b = 0; b < 8; b++) atomicAdd(&d_out[b * 1024 + n], acc[b] + bn);
  }
}

// ---------- host ----------
extern "C" void kernel_launch(void* const* d_in, const int* in_sizes, int n_in,
                              void* d_out, int out_size, void* d_ws, size_t ws_size,
                              hipStream_t stream)
{
  (void)in_sizes; (void)n_in; (void)out_size; (void)ws_size;
  const float* x      = (const float*)d_in[0];
  const int* seq_lens = (const int*)d_in[1];
  const float* A      = (const float*)d_in[2];
  const float* enc_w1 = (const float*)d_in[3];
  const float* enc_b1 = (const float*)d_in[4];
  const float* enc_w2 = (const float*)d_in[5];
  const float* enc_b2 = (const float*)d_in[6];
  const float* proj_w = (const float*)d_in[7];
  const float* proj_b = (const float*)d_in[8];
  const float* ln1_g  = (const float*)d_in[9];
  const float* ln1_b  = (const float*)d_in[10];
  const float* ffn_w1 = (const float*)d_in[11];
  const float* ffn_b1 = (const float*)d_in[12];
  const float* ffn_w2 = (const float*)d_in[13];
  const float* ffn_b2 = (const float*)d_in[14];
  const float* ln2_g  = (const float*)d_in[15];
  const float* ln2_b  = (const float*)d_in[16];
  const float* out_w  = (const float*)d_in[17];
  const float* out_b  = (const float*)d_in[18];

  char* p = (char*)d_ws;
  auto alloc = [&](size_t bytes) { char* r = p; p += (bytes + 255) & ~(size_t)255; return r; };
  short* h_mid = (short*)alloc(32768ull * 1024 * 2);  // encoder mid, bf16
  short* seqs  = (short*)alloc(32768ull * 128 * 2);   // Bx_t, bf16
  short* w1T   = (short*)alloc(1024ull * 384 * 2);
  short* w2T   = (short*)alloc(128ull * 1024 * 2);
  short* projB = (short*)alloc(128ull * 1024 * 2);
  short* ffn1B = (short*)alloc(1024ull * 512 * 2);
  short* ffn2B = (short*)alloc(512ull * 1024 * 2);
  short* outB  = (short*)alloc(1024ull * 1024 * 2);
  short* Spow  = (short*)alloc(12ull * 16384 * 2);
  short* SpowT = (short*)alloc(12ull * 16384 * 2);
  short* P1    = (short*)alloc(128ull * 8192 * 2);    // [i][(63-e)*128+j] = A^e, bf16
  short* P1t   = (short*)alloc(8192ull * 128 * 2);
  short* P2t   = (short*)alloc(8192ull * 128 * 2);
  // ---- zeroed zone (contiguous, all sizes 256-multiples) ----
  float* V       = (float*)alloc(512ull * 128 * 4);   // 256 KiB
  float* hFtail  = (float*)alloc(2ull * 8 * 128 * 4); // 8 KiB
  float* ffn1raw = (float*)alloc(8ull * 512 * 4);     // 16 KiB
  float* ffn2raw = (float*)alloc(8ull * 1024 * 4);    // 32 KiB
  // ---- end zone ----
  short* Vsh   = (short*)alloc(8192ull * 8 * 2);
  short* TlX   = (short*)alloc(8192ull * 8 * 2);
  float* projected = (float*)alloc(8ull * 1024 * 4);

  hipMemsetAsync(V, 0, (512ull * 128 + 2ull * 8 * 128 + 8ull * 512 + 8ull * 1024) * 4, stream);
  hipMemsetAsync(d_out, 0, 8192ull * 4, stream);

  prep_wide<<<10816, 256, 0, stream>>>(enc_w1, enc_w2, proj_w, ffn_w1, ffn_w2, out_w, A,
      w1T, w2T, projB, ffn1B, ffn2B, outB, P1, P1t, P2t, Spow, SpowT);
  pow_chain<<<1, 256, 0, stream>>>(Spow, SpowT);
  pow_fill<<<126, 256, 0, stream>>>(Spow, SpowT, P1, P1t, P2t);

  // encoder
  gemm_bt<1, 0><<<dim3(8, 256, 1), 256, 0, stream>>>(x, w1T, enc_b1, h_mid,
      384, 384, 1024, 12, 0, seq_lens, 1);
  gemm_bt<0, 1><<<dim3(1, 256, 1), 256, 0, stream>>>(h_mid, w2T, enc_b2, seqs,
      1024, 1024, 128, 32, 0, seq_lens, 1);

  // recurrence as GEMMs: per-chunk values, shifted combine, tail
  gemm_bt<0, 2><<<dim3(1, 4, 16), 256, 0, stream>>>(seqs, P1, nullptr, V,
      8192, 8192, 128, 16, 512, seq_lens, 0);
  build_shift<<<512, 256, 0, stream>>>(V, seqs, seq_lens, Vsh, TlX);
  tiny_gemm<<<32, 256, 0, stream>>>(Vsh, TlX, P2t, P1t, hFtail);

  // decoder (final_combine fused into proj_stage prologue)
  proj_stage<<<16, 256, 0, stream>>>(hFtail, P1t, seq_lens, projB, proj_b, projected);
  ffn1_stage<<<dim3(8, 4), 256, 0, stream>>>(projected, ln1_g, ln1_b, ffn1B, ffn1raw);
  ffn2_stage<<<dim3(16, 2), 256, 0, stream>>>(ffn1raw, ffn_b1, ffn2B, ffn2raw);
  out_stage<<<dim3(16, 2), 256, 0, stream>>>(ffn2raw, ffn_b2, projected, ln2_g, ln2_b,
      outB, out_b, (float*)d_out);
}

// Round 3
// 441.077 us; speedup vs baseline: 1.6433x; 1.0203x over previous
//
#include <hip/hip_runtime.h>

// ---------- types ----------
typedef __attribute__((ext_vector_type(8))) short short8;   // 8 bf16 (4 VGPR)
typedef __attribute__((ext_vector_type(4))) short short4v;  // 4 bf16
typedef __attribute__((ext_vector_type(4))) float float4v;  // 4 fp32

__device__ __forceinline__ float bf2f(short s) {
  union { float f; unsigned u; } cv; cv.u = ((unsigned)(unsigned short)s) << 16; return cv.f;
}
__device__ __forceinline__ short f2bf(float f) {   // RNE fp32->bf16, inputs never NaN
  union { float f; unsigned u; } cv; cv.f = f;
  unsigned u = cv.u;
  unsigned r = u + 0x7FFFu + ((u >> 16) & 1u);
  return (short)(r >> 16);
}
__device__ __forceinline__ float gelu_f(float v) {
  return 0.5f * v * (1.0f + erff(v * 0.70710678118654752440f));
}
// async global->LDS, 16 B per lane; LDS dest must be wave-uniform base (+lane*16 implicit)
__device__ __forceinline__ void glds16(const short* g, short* l) {
  __builtin_amdgcn_global_load_lds(
      (const __attribute__((address_space(1))) void*)g,
      (__attribute__((address_space(3))) void*)l, 16, 0, 0);
}

// ---------- MFMA GEMM: C[m][n] = sum_k A[m][k] * BT[n][k] ----------
// 128x128 tile, BK=64, global_load_lds(16B) staging, all-bf16 inputs.
// EPI: 0 = +bias, gelu, store bf16 ; 1 = +bias, store bf16 ; 2 = atomicAdd fp32 (split-K)
template<int EPI>
__global__ __launch_bounds__(256) void gemm_bt(
    const short* __restrict__ A_, const short* __restrict__ BT,
    const float* __restrict__ bias, void* __restrict__ out,
    int lda, int ldb, int ldc, int kSteps, int kChunk,
    const int* __restrict__ seq_lens, int seqSkip)
{
  int m0 = blockIdx.y * 128;
  int n0 = blockIdx.x * 128;
  if (seqSkip) {               // rows are (b*4096 + t); skip tiles fully past seq_len
    int b = m0 >> 12, t = m0 & 4095;
    if (t >= seq_lens[b]) return;
  }
  int kBase = blockIdx.z * kChunk;

  __shared__ __align__(16) short As[128 * 64];
  __shared__ __align__(16) short Bs[128 * 64];

  int tid = threadIdx.x;
  int lane = tid & 63, wave = tid >> 6;
  int l15 = lane & 15, quad = lane >> 4;
  int wm = wave & 1, wn = wave >> 1;   // wave quadrant (64x64)
  int lr = lane >> 3, lseg = lane & 7; // staging: 8 rows x 8 segs of 16B per issue

  float4v acc[4][4];
#pragma unroll
  for (int i = 0; i < 4; i++)
#pragma unroll
    for (int j = 0; j < 4; j++) acc[i][j] = 0;

  for (int ks = 0; ks < kSteps; ++ks) {
    int kk = kBase + ks * 64;
    // stage A,B tiles (128x64 bf16 = 16 KB each): 4 issues per matrix per thread
#pragma unroll
    for (int i = 0; i < 4; i++) {
      int rowg = wave * 32 + i * 8;             // wave-uniform row group base
      glds16(A_ + (size_t)(m0 + rowg + lr) * lda + kk + lseg * 8, &As[rowg * 64]);
      glds16(BT + (size_t)(n0 + rowg + lr) * ldb + kk + lseg * 8, &Bs[rowg * 64]);
    }
    __syncthreads();   // drains vmcnt (compiler emits full waitcnt before s_barrier)
#pragma unroll
    for (int kh = 0; kh < 2; kh++) {
      short8 af[4], bfr[4];
#pragma unroll
      for (int im = 0; im < 4; im++)
        af[im] = *(short8*)&As[(wm * 64 + im * 16 + l15) * 64 + kh * 32 + quad * 8];
#pragma unroll
      for (int in = 0; in < 4; in++)
        bfr[in] = *(short8*)&Bs[(wn * 64 + in * 16 + l15) * 64 + kh * 32 + quad * 8];
#pragma unroll
      for (int im = 0; im < 4; im++)
#pragma unroll
        for (int in = 0; in < 4; in++)
          acc[im][in] = __builtin_amdgcn_mfma_f32_16x16x32_bf16(af[im], bfr[in], acc[im][in], 0, 0, 0);
    }
    __syncthreads();
  }

  // C/D layout: col = lane&15, row = quad*4 + reg
#pragma unroll
  for (int im = 0; im < 4; im++) {
#pragma unroll
    for (int in = 0; in < 4; in++) {
      int n = n0 + wn * 64 + in * 16 + l15;
#pragma unroll
      for (int reg = 0; reg < 4; reg++) {
        int m = m0 + wm * 64 + im * 16 + quad * 4 + reg;
        float v = acc[im][in][reg];
        if (EPI == 0) {
          v += bias[n]; v = gelu_f(v);
          ((short*)out)[(size_t)m * ldc + n] = f2bf(v);
        } else if (EPI == 1) {
          v += bias[n];
          ((short*)out)[(size_t)m * ldc + n] = f2bf(v);
        } else {
          atomicAdd((float*)out + (size_t)m * ldc + n, v);
        }
      }
    }
  }
}

// ---------- prep: x->bf16, weight conversions, identity/A seeds ----------
// ranges (in idx units): x/4 (3145728) w1T(393216) w2T(131072) projB(131072)
//                        ffn1B(524288) ffn2B(524288) outB(1048576) id+A(16384)
__global__ void prep_wide(const float* __restrict__ x, const float* __restrict__ w1,
                          const float* __restrict__ w2,
                          const float* __restrict__ proj_w, const float* __restrict__ ffn_w1,
                          const float* __restrict__ ffn_w2, const float* __restrict__ out_w,
                          const float* __restrict__ A,
                          short* __restrict__ xB,
                          short* __restrict__ w1T, short* __restrict__ w2T,
                          short* __restrict__ projB, short* __restrict__ ffn1B,
                          short* __restrict__ ffn2B, short* __restrict__ outB,
                          short* __restrict__ P1, short* __restrict__ P1t,
                          short* __restrict__ P2t,
                          short* __restrict__ Spow, short* __restrict__ SpowT)
{
  int idx = blockIdx.x * 256 + threadIdx.x;
  if (idx < 3145728) {                       // x -> bf16, 4 elements/thread
    float4v v = ((const float4v*)x)[idx];
    short4v o;
#pragma unroll
    for (int j = 0; j < 4; j++) o[j] = f2bf(v[j]);
    ((short4v*)xB)[idx] = o;
    return;
  }
  idx -= 3145728;
  if (idx < 393216) {                        // w1T[n][k] = w1[k][n]
    int n = idx / 384, k = idx % 384;
    w1T[idx] = f2bf(w1[k * 1024 + n]);
    return;
  }
  idx -= 393216;
  if (idx < 131072) {                        // w2T[n][k] = w2[k][n]
    int n = idx / 1024, k = idx % 1024;
    w2T[idx] = f2bf(w2[k * 128 + n]);
    return;
  }
  idx -= 131072;
  if (idx < 131072) { projB[idx] = f2bf(proj_w[idx]); return; }
  idx -= 131072;
  if (idx < 524288) { ffn1B[idx] = f2bf(ffn_w1[idx]); return; }
  idx -= 524288;
  if (idx < 524288) { ffn2B[idx] = f2bf(ffn_w2[idx]); return; }
  idx -= 524288;
  if (idx < 1048576) { outB[idx] = f2bf(out_w[idx]); return; }
  idx -= 1048576;
  if (idx < 16384) {                         // identity slots (e=0) + A seed
    int i = idx >> 7, j = idx & 127;
    short bidv = f2bf((i == j) ? 1.0f : 0.0f);
    P1[i * 8192 + 63 * 128 + j] = bidv;
    P1t[(63 * 128 + j) * 128 + i] = bidv;
    P2t[(63 * 128 + j) * 128 + i] = bidv;
    short ab = f2bf(A[idx]);
    Spow[idx] = ab;                          // A^1 row-major
    SpowT[(size_t)j * 128 + i] = ab;         // transposed
  }
}

// ---------- single-block MFMA squaring chain ----------
// Spow[k]: k=0..6 -> A^(2^k) (A^1..A^64); k=7..11 -> M^(2^(k-6)) with M=A^64.
__global__ __launch_bounds__(256) void pow_chain(short* __restrict__ Spow,
                                                 short* __restrict__ SpowT)
{
  __shared__ short X[16384];    // cur, row-major
  __shared__ short XT[16384];   // cur, transposed
  int t = threadIdx.x;
  for (int i = t * 8; i < 16384; i += 2048) {
    *(short8*)&X[i]  = *(const short8*)&Spow[i];
    *(short8*)&XT[i] = *(const short8*)&SpowT[i];
  }
  __syncthreads();
  int lane = t & 63, wave = t >> 6, l15 = lane & 15, quad = lane >> 4;
  for (int step = 1; step <= 11; ++step) {
    short8 af[2][4], bfr[8][4];
#pragma unroll
    for (int mt = 0; mt < 2; mt++)
#pragma unroll
      for (int ks = 0; ks < 4; ks++)
        af[mt][ks] = *(short8*)&X[(wave * 32 + mt * 16 + l15) * 128 + ks * 32 + quad * 8];
#pragma unroll
    for (int nt = 0; nt < 8; nt++)
#pragma unroll
      for (int ks = 0; ks < 4; ks++)
        bfr[nt][ks] = *(short8*)&XT[(nt * 16 + l15) * 128 + ks * 32 + quad * 8];
    __syncthreads();                       // all frag loads done before in-place overwrite
    float4v acc[2][8];
#pragma unroll
    for (int mt = 0; mt < 2; mt++)
#pragma unroll
      for (int nt = 0; nt < 8; nt++) acc[mt][nt] = 0;
#pragma unroll
    for (int ks = 0; ks < 4; ks++)
#pragma unroll
      for (int mt = 0; mt < 2; mt++)
#pragma unroll
        for (int nt = 0; nt < 8; nt++)
          acc[mt][nt] = __builtin_amdgcn_mfma_f32_16x16x32_bf16(af[mt][ks], bfr[nt][ks], acc[mt][nt], 0, 0, 0);
    short* gX  = Spow  + (size_t)step * 16384;
    short* gXT = SpowT + (size_t)step * 16384;
#pragma unroll
    for (int mt = 0; mt < 2; mt++)
#pragma unroll
      for (int nt = 0; nt < 8; nt++)
#pragma unroll
        for (int reg = 0; reg < 4; reg++) {
          int m = wave * 32 + mt * 16 + quad * 4 + reg;
          int n = nt * 16 + l15;
          short v = f2bf(acc[mt][nt][reg]);
          X[m * 128 + n] = v; XT[n * 128 + m] = v;
          gX[m * 128 + n] = v; gXT[n * 128 + m] = v;
        }
    __syncthreads();
  }
}

// ---------- wide fill: block computes one table slot via seed-product chain ----------
__global__ __launch_bounds__(256) void pow_fill(const short* __restrict__ Spow,
                                                const short* __restrict__ SpowT,
                                                short* __restrict__ P1,
                                                short* __restrict__ P1t,
                                                short* __restrict__ P2t)
{
  __shared__ short cur[16384];
  __shared__ short Bt[16384];
  int bid = blockIdx.x;
  int table1 = bid < 63;
  int e = table1 ? bid + 1 : bid - 62;
  int t = threadIdx.x;
  int lane = t & 63, wave = t >> 6, l15 = lane & 15, quad = lane >> 4;

  int bits = e;
  int k0 = __ffs(bits) - 1; bits &= bits - 1;
  int s0 = table1 ? k0 : (k0 == 0 ? 6 : 6 + k0);
  for (int i = t * 8; i < 16384; i += 2048)
    *(short8*)&cur[i] = *(const short8*)&Spow[(size_t)s0 * 16384 + i];

  while (bits) {
    int k = __ffs(bits) - 1; bits &= bits - 1;
    int si = table1 ? k : (k == 0 ? 6 : 6 + k);
    for (int i = t * 8; i < 16384; i += 2048)
      *(short8*)&Bt[i] = *(const short8*)&SpowT[(size_t)si * 16384 + i];
    __syncthreads();
    short8 af[2][4], bfr[8][4];
#pragma unroll
    for (int mt = 0; mt < 2; mt++)
#pragma unroll
      for (int ks = 0; ks < 4; ks++)
        af[mt][ks] = *(short8*)&cur[(wave * 32 + mt * 16 + l15) * 128 + ks * 32 + quad * 8];
#pragma unroll
    for (int nt = 0; nt < 8; nt++)
#pragma unroll
      for (int ks = 0; ks < 4; ks++)
        bfr[nt][ks] = *(short8*)&Bt[(nt * 16 + l15) * 128 + ks * 32 + quad * 8];
    __syncthreads();                       // loads done before in-place write of cur
    float4v acc[2][8];
#pragma unroll
    for (int mt = 0; mt < 2; mt++)
#pragma unroll
      for (int nt = 0; nt < 8; nt++) acc[mt][nt] = 0;
#pragma unroll
    for (int ks = 0; ks < 4; ks++)
#pragma unroll
      for (int mt = 0; mt < 2; mt++)
#pragma unroll
        for (int nt = 0; nt < 8; nt++)
          acc[mt][nt] = __builtin_amdgcn_mfma_f32_16x16x32_bf16(af[mt][ks], bfr[nt][ks], acc[mt][nt], 0, 0, 0);
#pragma unroll
    for (int mt = 0; mt < 2; mt++)
#pragma unroll
      for (int nt = 0; nt < 8; nt++)
#pragma unroll
        for (int reg = 0; reg < 4; reg++) {
          int m = wave * 32 + mt * 16 + quad * 4 + reg;
          int n = nt * 16 + l15;
          cur[m * 128 + n] = f2bf(acc[mt][nt][reg]);
        }
    __syncthreads();
  }
  __syncthreads();
  int slot = 63 - e;
  for (int idx = t; idx < 16384; idx += 256) {
    int i = idx >> 7, j = idx & 127;
    short v = cur[idx];
    if (table1) {
      P1[i * 8192 + slot * 128 + j] = v;
      P1t[(slot * 128 + j) * 128 + i] = v;
    } else {
      P2t[(slot * 128 + j) * 128 + i] = v;
    }
  }
}

// ---------- build shifted/masked inputs for chunk-combine + tail ----------
__global__ void build_shift(const float* __restrict__ V, const short* __restrict__ seqs,
                            const int* __restrict__ seq_lens,
                            short* __restrict__ Vsh, short* __restrict__ TlX)
{
  int idx = blockIdx.x * 256 + threadIdx.x;   // 0..131071
  int pp = idx >> 16;
  int e = idx & 65535;
  int k = e >> 3, b = e & 7;
  int cp = k >> 7, i = k & 127;
  int L = seq_lens[b];
  short v = 0;
  if (pp == 0) {
    int F = L >> 6;
    int sh = 64 - F;
    if (cp >= sh) v = f2bf(V[(size_t)(b * 64 + (cp - sh)) * 128 + i]);
    Vsh[e] = v;
  } else {
    int F = L >> 6, rr = L & 63;
    int sh = 64 - rr;
    if (cp >= sh) v = seqs[((size_t)b * 4096 + F * 64 + (cp - sh)) * 128 + i];
    TlX[e] = v;
  }
}

// ---------- tiny split-K GEMMs: h_F = Vsh x P2, tailsum = TlX x P1 ----------
__global__ __launch_bounds__(256) void tiny_gemm(
    const short* __restrict__ Vsh, const short* __restrict__ TlX,
    const short* __restrict__ P2t, const short* __restrict__ P1t,
    float* __restrict__ hFtail)
{
  int pp = blockIdx.x >> 4, ks = blockIdx.x & 15;
  const short* X = pp ? TlX : Vsh;     // [8192][8] bf16
  const short* P = pp ? P1t : P2t;     // [8192][128] bf16
  float* outp = hFtail + pp * 1024;    // [8][128]
  int i = threadIdx.x & 127, g = threadIdx.x >> 7;
  float acc[4] = {0, 0, 0, 0};
  for (int k = ks * 512; k < ks * 512 + 512; ++k) {
    float pv = bf2f(P[k * 128 + i]);
    short4v xv = *(const short4v*)(X + k * 8 + g * 4);
#pragma unroll
    for (int q = 0; q < 4; q++) acc[q] += bf2f(xv[q]) * pv;
  }
#pragma unroll
  for (int q = 0; q < 4; q++) atomicAdd(&outp[(g * 4 + q) * 128 + i], acc[q]);
}

// ---------- decoder stage 1: h = A^rr hF + tail (recomputed per block), proj matvec ----------
__global__ __launch_bounds__(256) void proj_stage(
    const float* __restrict__ hFtail, const short* __restrict__ P1t,
    const int* __restrict__ seq_lens, const short* __restrict__ projB,
    const float* __restrict__ proj_b, float* __restrict__ projected)
{
  __shared__ short hT[128 * 8];        // bf16 [k][b]
  __shared__ float red[4][64][8];
  int t = threadIdx.x;
  {
    int b = t >> 5, i4 = (t & 31) * 4;
    int rr = seq_lens[b] & 63;
    const short* M = P1t + (size_t)(63 - rr) * 128 * 128;   // (A^rr)[i][j] = M[j*128+i]
    const float* hF = hFtail + b * 128;
    float acc[4];
#pragma unroll
    for (int q = 0; q < 4; q++) acc[q] = hFtail[1024 + b * 128 + i4 + q];  // tail
    for (int j = 0; j < 128; ++j) {
      float hv = hF[j];
      short4v mv = *(const short4v*)&M[j * 128 + i4];
#pragma unroll
      for (int q = 0; q < 4; q++) acc[q] += bf2f(mv[q]) * hv;
    }
#pragma unroll
    for (int q = 0; q < 4; q++) hT[(i4 + q) * 8 + b] = f2bf(acc[q]);
  }
  __syncthreads();
  int c = t & 63, sl = t >> 6;
  int n = blockIdx.x * 64 + c;
  float acc[8] = {0, 0, 0, 0, 0, 0, 0, 0};
  for (int k = sl * 32; k < sl * 32 + 32; ++k) {
    short8 xv = *(short8*)&hT[k * 8];
    float wv = bf2f(projB[k * 1024 + n]);
#pragma unroll
    for (int b = 0; b < 8; b++) acc[b] += bf2f(xv[b]) * wv;
  }
#pragma unroll
  for (int b = 0; b < 8; b++) red[sl][c][b] = acc[b];
  __syncthreads();
  if (sl == 0) {
#pragma unroll
    for (int s = 1; s < 4; s++)
#pragma unroll
      for (int b = 0; b < 8; b++) acc[b] += red[s][c][b];
    float bn = proj_b[n];
#pragma unroll
    for (int b = 0; b < 8; b++) projected[b * 1024 + n] = acc[b] + bn;
  }
}

// ---------- decoder stage 2: LN1(projected) @ ffn_w1 -> ffn1raw (split-K atomics) ----------
__global__ __launch_bounds__(256) void ffn1_stage(
    const float* __restrict__ projected, const float* __restrict__ g1,
    const float* __restrict__ b1, const short* __restrict__ ffn1B,
    float* __restrict__ ffn1raw)
{
  __shared__ float part[8][32][2];
  __shared__ float stats[8][2];
  __shared__ short xT[256 * 8];
  __shared__ float red[4][64][8];
  int t = threadIdx.x;
  { int b = t >> 5, j0 = t & 31; float s = 0, q = 0;
    for (int k = j0 * 32; k < j0 * 32 + 32; ++k) { float v = projected[b * 1024 + k]; s += v; q += v * v; }
    part[b][j0][0] = s; part[b][j0][1] = q; }
  __syncthreads();
  if (t < 8) {
    float s = 0, q = 0;
    for (int j = 0; j < 32; j++) { s += part[t][j][0]; q += part[t][j][1]; }
    float mu = s * (1.0f / 1024.0f);
    float var = q * (1.0f / 1024.0f) - mu * mu;
    stats[t][0] = mu; stats[t][1] = rsqrtf(var + 1e-5f);
  }
  __syncthreads();
  int ky0 = blockIdx.y * 256;
  for (int idx = t; idx < 2048; idx += 256) {
    int kl = idx >> 3, b = idx & 7; int k = ky0 + kl;
    float v = (projected[b * 1024 + k] - stats[b][0]) * stats[b][1] * g1[k] + b1[k];
    xT[kl * 8 + b] = f2bf(v);
  }
  __syncthreads();
  int c = t & 63, sl = t >> 6;
  int n = blockIdx.x * 64 + c;
  float acc[8] = {0, 0, 0, 0, 0, 0, 0, 0};
  for (int kl = sl * 64; kl < sl * 64 + 64; ++kl) {
    short8 xv = *(short8*)&xT[kl * 8];
    float wv = bf2f(ffn1B[(size_t)(ky0 + kl) * 512 + n]);
#pragma unroll
    for (int b = 0; b < 8; b++) acc[b] += bf2f(xv[b]) * wv;
  }
#pragma unroll
  for (int b = 0; b < 8; b++) red[sl][c][b] = acc[b];
  __syncthreads();
  if (sl == 0) {
#pragma unroll
    for (int s = 1; s < 4; s++)
#pragma unroll
      for (int b = 0; b < 8; b++) acc[b] += red[s][c][b];
#pragma unroll
    for (int b = 0; b < 8; b++) atomicAdd(&ffn1raw[b * 512 + n], acc[b]);
  }
}

// ---------- decoder stage 3: gelu(ffn1raw + b1) @ ffn_w2 -> ffn2raw ----------
__global__ __launch_bounds__(256) void ffn2_stage(
    const float* __restrict__ ffn1raw, const float* __restrict__ fb1,
    const short* __restrict__ ffn2B, float* __restrict__ ffn2raw)
{
  __shared__ short xT[256 * 8];
  __shared__ float red[4][64][8];
  int t = threadIdx.x;
  int ky0 = blockIdx.y * 256;
  for (int idx = t; idx < 2048; idx += 256) {
    int kl = idx >> 3, b = idx & 7; int k = ky0 + kl;
    float v = gelu_f(ffn1raw[b * 512 + k] + fb1[k]);
    xT[kl * 8 + b] = f2bf(v);
  }
  __syncthreads();
  int c = t & 63, sl = t >> 6;
  int n = blockIdx.x * 64 + c;
  float acc[8] = {0, 0, 0, 0, 0, 0, 0, 0};
  for (int kl = sl * 64; kl < sl * 64 + 64; ++kl) {
    short8 xv = *(short8*)&xT[kl * 8];
    float wv = bf2f(ffn2B[(size_t)(ky0 + kl) * 1024 + n]);
#pragma unroll
    for (int b = 0; b < 8; b++) acc[b] += bf2f(xv[b]) * wv;
  }
#pragma unroll
  for (int b = 0; b < 8; b++) red[sl][c][b] = acc[b];
  __syncthreads();
  if (sl == 0) {
#pragma unroll
    for (int s = 1; s < 4; s++)
#pragma unroll
      for (int b = 0; b < 8; b++) acc[b] += red[s][c][b];
#pragma unroll
    for (int b = 0; b < 8; b++) atomicAdd(&ffn2raw[b * 1024 + n], acc[b]);
  }
}

// ---------- decoder stage 4: LN2(ffn2raw + b2 + projected) @ out_w + out_b -> d_out ----------
__global__ __launch_bounds__(256) void out_stage(
    const float* __restrict__ ffn2raw, const float* __restrict__ fb2,
    const float* __restrict__ projected, const float* __restrict__ g2,
    const float* __restrict__ b2ln, const short* __restrict__ outB,
    const float* __restrict__ out_b, float* __restrict__ d_out)
{
  __shared__ float part[8][32][2];
  __shared__ float stats[8][2];
  __shared__ short xT[512 * 8];
  __shared__ float red[4][64][8];
  int t = threadIdx.x;
  { int b = t >> 5, j0 = t & 31; float s = 0, q = 0;
    for (int k = j0 * 32; k < j0 * 32 + 32; ++k) {
      float v = ffn2raw[b * 1024 + k] + fb2[k] + projected[b * 1024 + k];
      s += v; q += v * v;
    }
    part[b][j0][0] = s; part[b][j0][1] = q; }
  __syncthreads();
  if (t < 8) {
    float s = 0, q = 0;
    for (int j = 0; j < 32; j++) { s += part[t][j][0]; q += part[t][j][1]; }
    float mu = s * (1.0f / 1024.0f);
    float var = q * (1.0f / 1024.0f) - mu * mu;
    stats[t][0] = mu; stats[t][1] = rsqrtf(var + 1e-5f);
  }
  __syncthreads();
  int ky0 = blockIdx.y * 512;
  for (int idx = t; idx < 4096; idx += 256) {
    int kl = idx >> 3, b = idx & 7; int k = ky0 + kl;
    float v = ffn2raw[b * 1024 + k] + fb2[k] + projected[b * 1024 + k];
    v = (v - stats[b][0]) * stats[b][1] * g2[k] + b2ln[k];
    xT[kl * 8 + b] = f2bf(v);
  }
  __syncthreads();
  int c = t & 63, sl = t >> 6;
  int n = blockIdx.x * 64 + c;
  float acc[8] = {0, 0, 0, 0, 0, 0, 0, 0};
  for (int kl = sl * 128; kl < sl * 128 + 128; ++kl) {
    short8 xv = *(short8*)&xT[kl * 8];
    float wv = bf2f(outB[(size_t)(ky0 + kl) * 1024 + n]);
#pragma unroll
    for (int b = 0; b < 8; b++) acc[b] += bf2f(xv[b]) * wv;
  }
#pragma unroll
  for (int b = 0; b < 8; b++) red[sl][c][b] = acc[b];
  __syncthreads();
  if (sl == 0) {
#pragma unroll
    for (int s = 1; s < 4; s++)
#pragma unroll
      for (int b = 0; b < 8; b++) acc[b] += red[s][c][b];
    float bn = (blockIdx.y == 0) ? out_b[n] : 0.0f;
#pragma unroll
    for (int b = 0; b < 8; b++) atomicAdd(&d_out[b * 1024 + n], acc[b] + bn);
  }
}

// ---------- host ----------
extern "C" void kernel_launch(void* const* d_in, const int* in_sizes, int n_in,
                              void* d_out, int out_size, void* d_ws, size_t ws_size,
                              hipStream_t stream)
{
  (void)in_sizes; (void)n_in; (void)out_size; (void)ws_size;
  const float* x      = (const float*)d_in[0];
  const int* seq_lens = (const int*)d_in[1];
  const float* A      = (const float*)d_in[2];
  const float* enc_w1 = (const float*)d_in[3];
  const float* enc_b1 = (const float*)d_in[4];
  const float* enc_w2 = (const float*)d_in[5];
  const float* enc_b2 = (const float*)d_in[6];
  const float* proj_w = (const float*)d_in[7];
  const float* proj_b = (const float*)d_in[8];
  const float* ln1_g  = (const float*)d_in[9];
  const float* ln1_b  = (const float*)d_in[10];
  const float* ffn_w1 = (const float*)d_in[11];
  const float* ffn_b1 = (const float*)d_in[12];
  const float* ffn_w2 = (const float*)d_in[13];
  const float* ffn_b2 = (const float*)d_in[14];
  const float* ln2_g  = (const float*)d_in[15];
  const float* ln2_b  = (const float*)d_in[16];
  const float* out_w  = (const float*)d_in[17];
  const float* out_b  = (const float*)d_in[18];

  char* p = (char*)d_ws;
  auto alloc = [&](size_t bytes) { char* r = p; p += (bytes + 255) & ~(size_t)255; return r; };
  short* h_mid = (short*)alloc(32768ull * 1024 * 2);  // encoder mid, bf16
  short* xB    = (short*)alloc(32768ull * 384 * 2);   // x as bf16
  short* seqs  = (short*)alloc(32768ull * 128 * 2);   // Bx_t, bf16
  short* w1T   = (short*)alloc(1024ull * 384 * 2);
  short* w2T   = (short*)alloc(128ull * 1024 * 2);
  short* projB = (short*)alloc(128ull * 1024 * 2);
  short* ffn1B = (short*)alloc(1024ull * 512 * 2);
  short* ffn2B = (short*)alloc(512ull * 1024 * 2);
  short* outB  = (short*)alloc(1024ull * 1024 * 2);
  short* Spow  = (short*)alloc(12ull * 16384 * 2);
  short* SpowT = (short*)alloc(12ull * 16384 * 2);
  short* P1    = (short*)alloc(128ull * 8192 * 2);    // [i][(63-e)*128+j] = A^e, bf16
  short* P1t   = (short*)alloc(8192ull * 128 * 2);
  short* P2t   = (short*)alloc(8192ull * 128 * 2);
  // ---- zeroed zone (contiguous, all sizes 256-multiples) ----
  float* V       = (float*)alloc(512ull * 128 * 4);   // 256 KiB
  float* hFtail  = (float*)alloc(2ull * 8 * 128 * 4); // 8 KiB
  float* ffn1raw = (float*)alloc(8ull * 512 * 4);     // 16 KiB
  float* ffn2raw = (float*)alloc(8ull * 1024 * 4);    // 32 KiB
  // ---- end zone ----
  short* Vsh   = (short*)alloc(8192ull * 8 * 2);
  short* TlX   = (short*)alloc(8192ull * 8 * 2);
  float* projected = (float*)alloc(8ull * 1024 * 4);

  hipMemsetAsync(V, 0, (512ull * 128 + 2ull * 8 * 128 + 8ull * 512 + 8ull * 1024) * 4, stream);
  hipMemsetAsync(d_out, 0, 8192ull * 4, stream);

  prep_wide<<<23104, 256, 0, stream>>>(x, enc_w1, enc_w2, proj_w, ffn_w1, ffn_w2, out_w, A,
      xB, w1T, w2T, projB, ffn1B, ffn2B, outB, P1, P1t, P2t, Spow, SpowT);
  pow_chain<<<1, 256, 0, stream>>>(Spow, SpowT);
  pow_fill<<<126, 256, 0, stream>>>(Spow, SpowT, P1, P1t, P2t);

  // encoder
  gemm_bt<0><<<dim3(8, 256, 1), 256, 0, stream>>>(xB, w1T, enc_b1, h_mid,
      384, 384, 1024, 6, 0, seq_lens, 1);
  gemm_bt<1><<<dim3(1, 256, 1), 256, 0, stream>>>(h_mid, w2T, enc_b2, seqs,
      1024, 1024, 128, 16, 0, seq_lens, 1);

  // recurrence as GEMMs: per-chunk values, shifted combine, tail
  gemm_bt<2><<<dim3(1, 4, 16), 256, 0, stream>>>(seqs, P1, nullptr, V,
      8192, 8192, 128, 8, 512, seq_lens, 0);
  build_shift<<<512, 256, 0, stream>>>(V, seqs, seq_lens, Vsh, TlX);
  tiny_gemm<<<32, 256, 0, stream>>>(Vsh, TlX, P2t, P1t, hFtail);

  // decoder (final_combine fused into proj_stage prologue)
  proj_stage<<<16, 256, 0, stream>>>(hFtail, P1t, seq_lens, projB, proj_b, projected);
  ffn1_stage<<<dim3(8, 4), 256, 0, stream>>>(projected, ln1_g, ln1_b, ffn1B, ffn1raw);
  ffn2_stage<<<dim3(16, 2), 256, 0, stream>>>(ffn1raw, ffn_b1, ffn2B, ffn2raw);
  out_stage<<<dim3(16, 2), 256, 0, stream>>>(ffn2raw, ffn_b2, projected, ln2_g, ln2_b,
      outB, out_b, (float*)d_out);
}

// Round 4
// 428.864 us; speedup vs baseline: 1.6901x; 1.0285x over previous
//
#include <hip/hip_runtime.h>

// ---------- types ----------
typedef __attribute__((ext_vector_type(8))) short short8;   // 8 bf16 (4 VGPR)
typedef __attribute__((ext_vector_type(4))) short short4v;  // 4 bf16
typedef __attribute__((ext_vector_type(4))) float float4v;  // 4 fp32

__device__ __forceinline__ float bf2f(short s) {
  union { float f; unsigned u; } cv; cv.u = ((unsigned)(unsigned short)s) << 16; return cv.f;
}
__device__ __forceinline__ short f2bf(float f) {   // RNE fp32->bf16, inputs never NaN
  union { float f; unsigned u; } cv; cv.f = f;
  unsigned u = cv.u;
  unsigned r = u + 0x7FFFu + ((u >> 16) & 1u);
  return (short)(r >> 16);
}
__device__ __forceinline__ float gelu_f(float v) {
  return 0.5f * v * (1.0f + erff(v * 0.70710678118654752440f));
}
// async global->LDS, 16 B per lane; LDS dest = wave-uniform base + lane*16
__device__ __forceinline__ void glds16(const short* g, short* l) {
  __builtin_amdgcn_global_load_lds(
      (const __attribute__((address_space(1))) void*)g,
      (__attribute__((address_space(3))) void*)l, 16, 0, 0);
}

// ---------- fused encoder: seqs[m][n] = (GELU(x@w1+b1)@w2+b2), 64x128 out tile ----------
// LDS layouts are XOR-swizzled: tile[row][seg^(row&7)] (seg = 16B unit) -> frag reads <=2-way.
__global__ __launch_bounds__(256) void enc_fused(
    const short* __restrict__ xB, const short* __restrict__ w1T,
    const short* __restrict__ w2T, const float* __restrict__ b1,
    const float* __restrict__ b2, short* __restrict__ seqs,
    const int* __restrict__ seq_lens)
{
  int m0 = blockIdx.x * 64;
  { int b = m0 >> 12, t = m0 & 4095; if (t >= seq_lens[b]) return; }

  __shared__ __align__(16) short As[64 * 64];     // x tile, 8 KB
  __shared__ __align__(16) short Ws[128 * 64];    // w1/w2 chunk, 16 KB
  __shared__ __align__(16) short midb[64 * 128];  // GELU-mid chunk, 16 KB

  int tid = threadIdx.x, lane = tid & 63, wave = tid >> 6;
  int l15 = lane & 15, quad = lane >> 4;
  int lr = lane >> 3, lseg = lane & 7;

  float4v accO[4][2];
#pragma unroll
  for (int i = 0; i < 4; i++)
#pragma unroll
    for (int j = 0; j < 2; j++) accO[i][j] = 0;

  for (int nc = 0; nc < 8; ++nc) {
    float4v accM[4][2];
#pragma unroll
    for (int i = 0; i < 4; i++)
#pragma unroll
      for (int j = 0; j < 2; j++) accM[i][j] = 0;

    // ---- GEMM1 chunk: mid[64][128] = x[64][384] @ w1T[nc*128..+128][384]^T ----
    for (int ks = 0; ks < 6; ++ks) {
      int kk = ks * 64;
#pragma unroll
      for (int i = 0; i < 2; i++) {                 // x: 64 rows
        int rowg = wave * 16 + i * 8;
        glds16(xB + (size_t)(m0 + rowg + lr) * 384 + kk + (lseg ^ lr) * 8, &As[rowg * 64]);
      }
#pragma unroll
      for (int i = 0; i < 4; i++) {                 // w1 chunk: 128 rows
        int rowg = wave * 32 + i * 8;
        glds16(w1T + (size_t)(nc * 128 + rowg + lr) * 384 + kk + (lseg ^ lr) * 8, &Ws[rowg * 64]);
      }
      __syncthreads();
#pragma unroll
      for (int kh = 0; kh < 2; kh++) {
        int s = kh * 4 + quad;
        short8 af[4], bfr[2];
#pragma unroll
        for (int im = 0; im < 4; im++) {
          int r = im * 16 + l15;
          af[im] = *(short8*)&As[r * 64 + ((s ^ (r & 7)) * 8)];
        }
#pragma unroll
        for (int in = 0; in < 2; in++) {
          int r = wave * 32 + in * 16 + l15;
          bfr[in] = *(short8*)&Ws[r * 64 + ((s ^ (r & 7)) * 8)];
        }
#pragma unroll
        for (int im = 0; im < 4; im++)
#pragma unroll
          for (int in = 0; in < 2; in++)
            accM[im][in] = __builtin_amdgcn_mfma_f32_16x16x32_bf16(af[im], bfr[in], accM[im][in], 0, 0, 0);
      }
      __syncthreads();
    }
    // ---- GELU epilogue -> midb (A-operand layout, swizzled) ----
#pragma unroll
    for (int im = 0; im < 4; im++)
#pragma unroll
      for (int in = 0; in < 2; in++) {
        int k = wave * 32 + in * 16 + l15;          // mid column
        float bias = b1[nc * 128 + k];
#pragma unroll
        for (int reg = 0; reg < 4; reg++) {
          int m = im * 16 + quad * 4 + reg;
          float v = gelu_f(accM[im][in][reg] + bias);
          int s = k >> 3;
          int sw = (s & 8) | ((s & 7) ^ (m & 7));
          midb[m * 128 + sw * 8 + (k & 7)] = f2bf(v);
        }
      }
    __syncthreads();
    // ---- GEMM2 chunk: accO += mid[64][128] @ w2T[0..128][nc*128..+128]^T ----
#pragma unroll
    for (int ks2 = 0; ks2 < 2; ++ks2) {
      int kk = nc * 128 + ks2 * 64;
#pragma unroll
      for (int i = 0; i < 4; i++) {                 // w2 chunk: 128 rows (out cols)
        int rowg = wave * 32 + i * 8;
        glds16(w2T + (size_t)(rowg + lr) * 1024 + kk + (lseg ^ lr) * 8, &Ws[rowg * 64]);
      }
      __syncthreads();
#pragma unroll
      for (int kh = 0; kh < 2; kh++) {
        short8 af[4], bfr[2];
#pragma unroll
        for (int im = 0; im < 4; im++) {
          int m = im * 16 + l15;
          int kb = ks2 * 64 + kh * 32 + quad * 8;
          int s = kb >> 3;
          int sw = (s & 8) | ((s & 7) ^ (m & 7));
          af[im] = *(short8*)&midb[m * 128 + sw * 8];
        }
#pragma unroll
        for (int in = 0; in < 2; in++) {
          int r = wave * 32 + in * 16 + l15;
          int s = kh * 4 + quad;
          bfr[in] = *(short8*)&Ws[r * 64 + ((s ^ (r & 7)) * 8)];
        }
#pragma unroll
        for (int im = 0; im < 4; im++)
#pragma unroll
          for (int in = 0; in < 2; in++)
            accO[im][in] = __builtin_amdgcn_mfma_f32_16x16x32_bf16(af[im], bfr[in], accO[im][in], 0, 0, 0);
      }
      __syncthreads();
    }
  }
  // ---- final epilogue: +b2, store bf16 seqs ----
#pragma unroll
  for (int im = 0; im < 4; im++)
#pragma unroll
    for (int in = 0; in < 2; in++) {
      int n = wave * 32 + in * 16 + l15;
      float bias = b2[n];
#pragma unroll
      for (int reg = 0; reg < 4; reg++) {
        int m = m0 + im * 16 + quad * 4 + reg;
        seqs[(size_t)m * 128 + n] = f2bf(accO[im][in][reg] + bias);
      }
    }
}

// ---------- MFMA GEMM (V-GEMM): Vz[z][m][n] = sum_k A[m][k]*BT[n][k] over k-chunk z ----------
__global__ __launch_bounds__(256) void gemm_bt(
    const short* __restrict__ A_, const short* __restrict__ BT,
    float* __restrict__ out, int lda, int ldb, int ldc,
    int kSteps, int kChunk)
{
  int m0 = blockIdx.y * 128;
  int n0 = blockIdx.x * 128;
  int kBase = blockIdx.z * kChunk;

  __shared__ __align__(16) short As[128 * 64];
  __shared__ __align__(16) short Bs[128 * 64];

  int tid = threadIdx.x;
  int lane = tid & 63, wave = tid >> 6;
  int l15 = lane & 15, quad = lane >> 4;
  int wm = wave & 1, wn = wave >> 1;
  int lr = lane >> 3, lseg = lane & 7;

  float4v acc[4][4];
#pragma unroll
  for (int i = 0; i < 4; i++)
#pragma unroll
    for (int j = 0; j < 4; j++) acc[i][j] = 0;

  for (int ks = 0; ks < kSteps; ++ks) {
    int kk = kBase + ks * 64;
#pragma unroll
    for (int i = 0; i < 4; i++) {
      int rowg = wave * 32 + i * 8;
      glds16(A_ + (size_t)(m0 + rowg + lr) * lda + kk + (lseg ^ lr) * 8, &As[rowg * 64]);
      glds16(BT + (size_t)(n0 + rowg + lr) * ldb + kk + (lseg ^ lr) * 8, &Bs[rowg * 64]);
    }
    __syncthreads();
#pragma unroll
    for (int kh = 0; kh < 2; kh++) {
      int s = kh * 4 + quad;
      short8 af[4], bfr[4];
#pragma unroll
      for (int im = 0; im < 4; im++) {
        int r = wm * 64 + im * 16 + l15;
        af[im] = *(short8*)&As[r * 64 + ((s ^ (r & 7)) * 8)];
      }
#pragma unroll
      for (int in = 0; in < 4; in++) {
        int r = wn * 64 + in * 16 + l15;
        bfr[in] = *(short8*)&Bs[r * 64 + ((s ^ (r & 7)) * 8)];
      }
#pragma unroll
      for (int im = 0; im < 4; im++)
#pragma unroll
        for (int in = 0; in < 4; in++)
          acc[im][in] = __builtin_amdgcn_mfma_f32_16x16x32_bf16(af[im], bfr[in], acc[im][in], 0, 0, 0);
    }
    __syncthreads();
  }
  float* outz = out + (size_t)blockIdx.z * 65536;
#pragma unroll
  for (int im = 0; im < 4; im++)
#pragma unroll
    for (int in = 0; in < 4; in++) {
      int n = n0 + wn * 64 + in * 16 + l15;
#pragma unroll
      for (int reg = 0; reg < 4; reg++) {
        int m = m0 + wm * 64 + im * 16 + quad * 4 + reg;
        outz[(size_t)m * ldc + n] = acc[im][in][reg];
      }
    }
}

// ---------- prep: x->bf16, weight conversions, identity/A seeds ----------
__global__ void prep_wide(const float* __restrict__ x, const float* __restrict__ w1,
                          const float* __restrict__ w2,
                          const float* __restrict__ proj_w, const float* __restrict__ ffn_w1,
                          const float* __restrict__ ffn_w2, const float* __restrict__ out_w,
                          const float* __restrict__ A,
                          short* __restrict__ xB,
                          short* __restrict__ w1T, short* __restrict__ w2T,
                          short* __restrict__ projB, short* __restrict__ ffn1B,
                          short* __restrict__ ffn2B, short* __restrict__ outB,
                          short* __restrict__ P1, short* __restrict__ P1t,
                          short* __restrict__ P2t,
                          short* __restrict__ Spow, short* __restrict__ SpowT)
{
  int idx = blockIdx.x * 256 + threadIdx.x;
  if (idx < 3145728) {                       // x -> bf16, 4 elements/thread
    float4v v = ((const float4v*)x)[idx];
    short4v o;
#pragma unroll
    for (int j = 0; j < 4; j++) o[j] = f2bf(v[j]);
    ((short4v*)xB)[idx] = o;
    return;
  }
  idx -= 3145728;
  if (idx < 393216) {                        // w1T[n][k] = w1[k][n]
    int n = idx / 384, k = idx % 384;
    w1T[idx] = f2bf(w1[k * 1024 + n]);
    return;
  }
  idx -= 393216;
  if (idx < 131072) {                        // w2T[n][k] = w2[k][n]
    int n = idx / 1024, k = idx % 1024;
    w2T[idx] = f2bf(w2[k * 128 + n]);
    return;
  }
  idx -= 131072;
  if (idx < 131072) { projB[idx] = f2bf(proj_w[idx]); return; }
  idx -= 131072;
  if (idx < 524288) { ffn1B[idx] = f2bf(ffn_w1[idx]); return; }
  idx -= 524288;
  if (idx < 524288) { ffn2B[idx] = f2bf(ffn_w2[idx]); return; }
  idx -= 524288;
  if (idx < 1048576) { outB[idx] = f2bf(out_w[idx]); return; }
  idx -= 1048576;
  if (idx < 16384) {                         // identity slots (e=0) + A seed
    int i = idx >> 7, j = idx & 127;
    short bidv = f2bf((i == j) ? 1.0f : 0.0f);
    P1[i * 8192 + 63 * 128 + j] = bidv;
    P1t[(63 * 128 + j) * 128 + i] = bidv;
    P2t[(63 * 128 + j) * 128 + i] = bidv;
    short ab = f2bf(A[idx]);
    Spow[idx] = ab;                          // A^1 row-major
    SpowT[(size_t)j * 128 + i] = ab;         // transposed
  }
}

// ---------- single-block MFMA squaring chain ----------
// Spow[k]: k=0..6 -> A^(2^k); k=7..11 -> (A^64)^(2^(k-6)).
__global__ __launch_bounds__(256) void pow_chain(short* __restrict__ Spow,
                                                 short* __restrict__ SpowT)
{
  __shared__ short X[16384];    // cur, row-major
  __shared__ short XT[16384];   // cur, transposed
  int t = threadIdx.x;
  for (int i = t * 8; i < 16384; i += 2048) {
    *(short8*)&X[i]  = *(const short8*)&Spow[i];
    *(short8*)&XT[i] = *(const short8*)&SpowT[i];
  }
  __syncthreads();
  int lane = t & 63, wave = t >> 6, l15 = lane & 15, quad = lane >> 4;
  for (int step = 1; step <= 11; ++step) {
    short8 af[2][4], bfr[8][4];
#pragma unroll
    for (int mt = 0; mt < 2; mt++)
#pragma unroll
      for (int ks = 0; ks < 4; ks++)
        af[mt][ks] = *(short8*)&X[(wave * 32 + mt * 16 + l15) * 128 + ks * 32 + quad * 8];
#pragma unroll
    for (int nt = 0; nt < 8; nt++)
#pragma unroll
      for (int ks = 0; ks < 4; ks++)
        bfr[nt][ks] = *(short8*)&XT[(nt * 16 + l15) * 128 + ks * 32 + quad * 8];
    __syncthreads();                       // all frag loads done before in-place overwrite
    float4v acc[2][8];
#pragma unroll
    for (int mt = 0; mt < 2; mt++)
#pragma unroll
      for (int nt = 0; nt < 8; nt++) acc[mt][nt] = 0;
#pragma unroll
    for (int ks = 0; ks < 4; ks++)
#pragma unroll
      for (int mt = 0; mt < 2; mt++)
#pragma unroll
        for (int nt = 0; nt < 8; nt++)
          acc[mt][nt] = __builtin_amdgcn_mfma_f32_16x16x32_bf16(af[mt][ks], bfr[nt][ks], acc[mt][nt], 0, 0, 0);
    short* gX  = Spow  + (size_t)step * 16384;
    short* gXT = SpowT + (size_t)step * 16384;
#pragma unroll
    for (int mt = 0; mt < 2; mt++)
#pragma unroll
      for (int nt = 0; nt < 8; nt++)
#pragma unroll
        for (int reg = 0; reg < 4; reg++) {
          int m = wave * 32 + mt * 16 + quad * 4 + reg;
          int n = nt * 16 + l15;
          short v = f2bf(acc[mt][nt][reg]);
          X[m * 128 + n] = v; XT[n * 128 + m] = v;
          gX[m * 128 + n] = v; gXT[n * 128 + m] = v;
        }
    __syncthreads();
  }
}

// ---------- wide fill: block computes one table slot via seed-product chain ----------
__global__ __launch_bounds__(256) void pow_fill(const short* __restrict__ Spow,
                                                const short* __restrict__ SpowT,
                                                short* __restrict__ P1,
                                                short* __restrict__ P1t,
                                                short* __restrict__ P2t)
{
  __shared__ short cur[16384];
  __shared__ short Bt[16384];
  int bid = blockIdx.x;
  int table1 = bid < 63;
  int e = table1 ? bid + 1 : bid - 62;
  int t = threadIdx.x;
  int lane = t & 63, wave = t >> 6, l15 = lane & 15, quad = lane >> 4;

  int bits = e;
  int k0 = __ffs(bits) - 1; bits &= bits - 1;
  int s0 = table1 ? k0 : (k0 == 0 ? 6 : 6 + k0);
  for (int i = t * 8; i < 16384; i += 2048)
    *(short8*)&cur[i] = *(const short8*)&Spow[(size_t)s0 * 16384 + i];

  while (bits) {
    int k = __ffs(bits) - 1; bits &= bits - 1;
    int si = table1 ? k : (k == 0 ? 6 : 6 + k);
    for (int i = t * 8; i < 16384; i += 2048)
      *(short8*)&Bt[i] = *(const short8*)&SpowT[(size_t)si * 16384 + i];
    __syncthreads();
    short8 af[2][4], bfr[8][4];
#pragma unroll
    for (int mt = 0; mt < 2; mt++)
#pragma unroll
      for (int ks = 0; ks < 4; ks++)
        af[mt][ks] = *(short8*)&cur[(wave * 32 + mt * 16 + l15) * 128 + ks * 32 + quad * 8];
#pragma unroll
    for (int nt = 0; nt < 8; nt++)
#pragma unroll
      for (int ks = 0; ks < 4; ks++)
        bfr[nt][ks] = *(short8*)&Bt[(nt * 16 + l15) * 128 + ks * 32 + quad * 8];
    __syncthreads();                       // loads done before in-place write of cur
    float4v acc[2][8];
#pragma unroll
    for (int mt = 0; mt < 2; mt++)
#pragma unroll
      for (int nt = 0; nt < 8; nt++) acc[mt][nt] = 0;
#pragma unroll
    for (int ks = 0; ks < 4; ks++)
#pragma unroll
      for (int mt = 0; mt < 2; mt++)
#pragma unroll
        for (int nt = 0; nt < 8; nt++)
          acc[mt][nt] = __builtin_amdgcn_mfma_f32_16x16x32_bf16(af[mt][ks], bfr[nt][ks], acc[mt][nt], 0, 0, 0);
#pragma unroll
    for (int mt = 0; mt < 2; mt++)
#pragma unroll
      for (int nt = 0; nt < 8; nt++)
#pragma unroll
        for (int reg = 0; reg < 4; reg++) {
          int m = wave * 32 + mt * 16 + quad * 4 + reg;
          int n = nt * 16 + l15;
          cur[m * 128 + n] = f2bf(acc[mt][nt][reg]);
        }
    __syncthreads();
  }
  __syncthreads();
  int slot = 63 - e;
  for (int idx = t; idx < 16384; idx += 256) {
    int i = idx >> 7, j = idx & 127;
    short v = cur[idx];
    if (table1) {
      P1[i * 8192 + slot * 128 + j] = v;
      P1t[(slot * 128 + j) * 128 + i] = v;
    } else {
      P2t[(slot * 128 + j) * 128 + i] = v;
    }
  }
}

// ---------- combine: build shifted inputs in LDS (z-sum of Vz / tail from seqs) + GEMM ----------
// blocks: (pp=0: hF via P2) x 16 k-slices, (pp=1: tailsum via P1) x 16
__global__ __launch_bounds__(256) void combine_gemm(
    const float* __restrict__ Vz, const short* __restrict__ seqs,
    const int* __restrict__ seq_lens,
    const short* __restrict__ P2t, const short* __restrict__ P1t,
    float* __restrict__ hFtail)
{
  __shared__ short X[512 * 8];   // [k_local][b] bf16
  int pp = blockIdx.x >> 4, ks = blockIdx.x & 15;
  int t = threadIdx.x;
  for (int e = t; e < 4096; e += 256) {
    int klocal = e >> 3, b = e & 7;
    int cp = ks * 4 + (klocal >> 7), i = klocal & 127;
    int L = seq_lens[b];
    if (pp == 0) {
      int F = L >> 6, sh = 64 - F;
      float v = 0.f;
      if (cp >= sh) {
        int row = (b * 64 + (cp - sh)) * 128 + i;
#pragma unroll
        for (int z = 0; z < 16; z++) v += Vz[(size_t)z * 65536 + row];
      }
      X[e] = f2bf(v);
    } else {
      int F = L >> 6, rr = L & 63, sh = 64 - rr;
      short s = 0;
      if (cp >= sh) s = seqs[((size_t)b * 4096 + F * 64 + (cp - sh)) * 128 + i];
      X[e] = s;
    }
  }
  __syncthreads();
  const short* P = pp ? P1t : P2t;
  float* outp = hFtail + pp * 1024;
  int i = t & 127, g = t >> 7;
  float acc[4] = {0, 0, 0, 0};
  for (int kl = 0; kl < 512; ++kl) {
    int k = ks * 512 + kl;
    float pv = bf2f(P[k * 128 + i]);
    short4v xv = *(const short4v*)(X + kl * 8 + g * 4);
#pragma unroll
    for (int q = 0; q < 4; q++) acc[q] += bf2f(xv[q]) * pv;
  }
#pragma unroll
  for (int q = 0; q < 4; q++) atomicAdd(&outp[(g * 4 + q) * 128 + i], acc[q]);
}

// ---------- decoder stage 1: h = A^rr hF + tail, proj matvec ----------
__global__ __launch_bounds__(256) void proj_stage(
    const float* __restrict__ hFtail, const short* __restrict__ P1t,
    const int* __restrict__ seq_lens, const short* __restrict__ projB,
    const float* __restrict__ proj_b, float* __restrict__ projected)
{
  __shared__ short hT[128 * 8];        // bf16 [k][b]
  __shared__ float red[4][64][8];
  int t = threadIdx.x;
  {
    int b = t >> 5, i4 = (t & 31) * 4;
    int rr = seq_lens[b] & 63;
    const short* M = P1t + (size_t)(63 - rr) * 128 * 128;   // (A^rr)[i][j] = M[j*128+i]
    const float* hF = hFtail + b * 128;
    float acc[4];
#pragma unroll
    for (int q = 0; q < 4; q++) acc[q] = hFtail[1024 + b * 128 + i4 + q];  // tail
    for (int j = 0; j < 128; ++j) {
      float hv = hF[j];
      short4v mv = *(const short4v*)&M[j * 128 + i4];
#pragma unroll
      for (int q = 0; q < 4; q++) acc[q] += bf2f(mv[q]) * hv;
    }
#pragma unroll
    for (int q = 0; q < 4; q++) hT[(i4 + q) * 8 + b] = f2bf(acc[q]);
  }
  __syncthreads();
  int c = t & 63, sl = t >> 6;
  int n = blockIdx.x * 64 + c;
  float acc[8] = {0, 0, 0, 0, 0, 0, 0, 0};
  for (int k = sl * 32; k < sl * 32 + 32; ++k) {
    short8 xv = *(short8*)&hT[k * 8];
    float wv = bf2f(projB[k * 1024 + n]);
#pragma unroll
    for (int b = 0; b < 8; b++) acc[b] += bf2f(xv[b]) * wv;
  }
#pragma unroll
  for (int b = 0; b < 8; b++) red[sl][c][b] = acc[b];
  __syncthreads();
  if (sl == 0) {
#pragma unroll
    for (int s = 1; s < 4; s++)
#pragma unroll
      for (int b = 0; b < 8; b++) acc[b] += red[s][c][b];
    float bn = proj_b[n];
#pragma unroll
    for (int b = 0; b < 8; b++) projected[b * 1024 + n] = acc[b] + bn;
  }
}

// ---------- decoder stage 2: LN1(projected) @ ffn_w1 -> ffn1raw ----------
__global__ __launch_bounds__(256) void ffn1_stage(
    const float* __restrict__ projected, const float* __restrict__ g1,
    const float* __restrict__ b1, const short* __restrict__ ffn1B,
    float* __restrict__ ffn1raw)
{
  __shared__ float part[8][32][2];
  __shared__ float stats[8][2];
  __shared__ short xT[256 * 8];
  __shared__ float red[4][64][8];
  int t = threadIdx.x;
  { int b = t >> 5, j0 = t & 31; float s = 0, q = 0;
    for (int k = j0 * 32; k < j0 * 32 + 32; ++k) { float v = projected[b * 1024 + k]; s += v; q += v * v; }
    part[b][j0][0] = s; part[b][j0][1] = q; }
  __syncthreads();
  if (t < 8) {
    float s = 0, q = 0;
    for (int j = 0; j < 32; j++) { s += part[t][j][0]; q += part[t][j][1]; }
    float mu = s * (1.0f / 1024.0f);
    float var = q * (1.0f / 1024.0f) - mu * mu;
    stats[t][0] = mu; stats[t][1] = rsqrtf(var + 1e-5f);
  }
  __syncthreads();
  int ky0 = blockIdx.y * 256;
  for (int idx = t; idx < 2048; idx += 256) {
    int kl = idx >> 3, b = idx & 7; int k = ky0 + kl;
    float v = (projected[b * 1024 + k] - stats[b][0]) * stats[b][1] * g1[k] + b1[k];
    xT[kl * 8 + b] = f2bf(v);
  }
  __syncthreads();
  int c = t & 63, sl = t >> 6;
  int n = blockIdx.x * 64 + c;
  float acc[8] = {0, 0, 0, 0, 0, 0, 0, 0};
  for (int kl = sl * 64; kl < sl * 64 + 64; ++kl) {
    short8 xv = *(short8*)&xT[kl * 8];
    float wv = bf2f(ffn1B[(size_t)(ky0 + kl) * 512 + n]);
#pragma unroll
    for (int b = 0; b < 8; b++) acc[b] += bf2f(xv[b]) * wv;
  }
#pragma unroll
  for (int b = 0; b < 8; b++) red[sl][c][b] = acc[b];
  __syncthreads();
  if (sl == 0) {
#pragma unroll
    for (int s = 1; s < 4; s++)
#pragma unroll
      for (int b = 0; b < 8; b++) acc[b] += red[s][c][b];
#pragma unroll
    for (int b = 0; b < 8; b++) atomicAdd(&ffn1raw[b * 512 + n], acc[b]);
  }
}

// ---------- decoder stage 3: gelu(ffn1raw + b1) @ ffn_w2 -> ffn2raw ----------
__global__ __launch_bounds__(256) void ffn2_stage(
    const float* __restrict__ ffn1raw, const float* __restrict__ fb1,
    const short* __restrict__ ffn2B, float* __restrict__ ffn2raw)
{
  __shared__ short xT[256 * 8];
  __shared__ float red[4][64][8];
  int t = threadIdx.x;
  int ky0 = blockIdx.y * 256;
  for (int idx = t; idx < 2048; idx += 256) {
    int kl = idx >> 3, b = idx & 7; int k = ky0 + kl;
    float v = gelu_f(ffn1raw[b * 512 + k] + fb1[k]);
    xT[kl * 8 + b] = f2bf(v);
  }
  __syncthreads();
  int c = t & 63, sl = t >> 6;
  int n = blockIdx.x * 64 + c;
  float acc[8] = {0, 0, 0, 0, 0, 0, 0, 0};
  for (int kl = sl * 64; kl < sl * 64 + 64; ++kl) {
    short8 xv = *(short8*)&xT[kl * 8];
    float wv = bf2f(ffn2B[(size_t)(ky0 + kl) * 1024 + n]);
#pragma unroll
    for (int b = 0; b < 8; b++) acc[b] += bf2f(xv[b]) * wv;
  }
#pragma unroll
  for (int b = 0; b < 8; b++) red[sl][c][b] = acc[b];
  __syncthreads();
  if (sl == 0) {
#pragma unroll
    for (int s = 1; s < 4; s++)
#pragma unroll
      for (int b = 0; b < 8; b++) acc[b] += red[s][c][b];
#pragma unroll
    for (int b = 0; b < 8; b++) atomicAdd(&ffn2raw[b * 1024 + n], acc[b]);
  }
}

// ---------- decoder stage 4: LN2(ffn2raw + b2 + projected) @ out_w + out_b -> d_out ----------
__global__ __launch_bounds__(256) void out_stage(
    const float* __restrict__ ffn2raw, const float* __restrict__ fb2,
    const float* __restrict__ projected, const float* __restrict__ g2,
    const float* __restrict__ b2ln, const short* __restrict__ outB,
    const float* __restrict__ out_b, float* __restrict__ d_out)
{
  __shared__ float part[8][32][2];
  __shared__ float stats[8][2];
  __shared__ short xT[512 * 8];
  __shared__ float red[4][64][8];
  int t = threadIdx.x;
  { int b = t >> 5, j0 = t & 31; float s = 0, q = 0;
    for (int k = j0 * 32; k < j0 * 32 + 32; ++k) {
      float v = ffn2raw[b * 1024 + k] + fb2[k] + projected[b * 1024 + k];
      s += v; q += v * v;
    }
    part[b][j0][0] = s; part[b][j0][1] = q; }
  __syncthreads();
  if (t < 8) {
    float s = 0, q = 0;
    for (int j = 0; j < 32; j++) { s += part[t][j][0]; q += part[t][j][1]; }
    float mu = s * (1.0f / 1024.0f);
    float var = q * (1.0f / 1024.0f) - mu * mu;
    stats[t][0] = mu; stats[t][1] = rsqrtf(var + 1e-5f);
  }
  __syncthreads();
  int ky0 = blockIdx.y * 512;
  for (int idx = t; idx < 4096; idx += 256) {
    int kl = idx >> 3, b = idx & 7; int k = ky0 + kl;
    float v = ffn2raw[b * 1024 + k] + fb2[k] + projected[b * 1024 + k];
    v = (v - stats[b][0]) * stats[b][1] * g2[k] + b2ln[k];
    xT[kl * 8 + b] = f2bf(v);
  }
  __syncthreads();
  int c = t & 63, sl = t >> 6;
  int n = blockIdx.x * 64 + c;
  float acc[8] = {0, 0, 0, 0, 0, 0, 0, 0};
  for (int kl = sl * 128; kl < sl * 128 + 128; ++kl) {
    short8 xv = *(short8*)&xT[kl * 8];
    float wv = bf2f(outB[(size_t)(ky0 + kl) * 1024 + n]);
#pragma unroll
    for (int b = 0; b < 8; b++) acc[b] += bf2f(xv[b]) * wv;
  }
#pragma unroll
  for (int b = 0; b < 8; b++) red[sl][c][b] = acc[b];
  __syncthreads();
  if (sl == 0) {
#pragma unroll
    for (int s = 1; s < 4; s++)
#pragma unroll
      for (int b = 0; b < 8; b++) acc[b] += red[s][c][b];
    float bn = (blockIdx.y == 0) ? out_b[n] : 0.0f;
#pragma unroll
    for (int b = 0; b < 8; b++) atomicAdd(&d_out[b * 1024 + n], acc[b] + bn);
  }
}

// ---------- host ----------
extern "C" void kernel_launch(void* const* d_in, const int* in_sizes, int n_in,
                              void* d_out, int out_size, void* d_ws, size_t ws_size,
                              hipStream_t stream)
{
  (void)in_sizes; (void)n_in; (void)out_size; (void)ws_size;
  const float* x      = (const float*)d_in[0];
  const int* seq_lens = (const int*)d_in[1];
  const float* A      = (const float*)d_in[2];
  const float* enc_w1 = (const float*)d_in[3];
  const float* enc_b1 = (const float*)d_in[4];
  const float* enc_w2 = (const float*)d_in[5];
  const float* enc_b2 = (const float*)d_in[6];
  const float* proj_w = (const float*)d_in[7];
  const float* proj_b = (const float*)d_in[8];
  const float* ln1_g  = (const float*)d_in[9];
  const float* ln1_b  = (const float*)d_in[10];
  const float* ffn_w1 = (const float*)d_in[11];
  const float* ffn_b1 = (const float*)d_in[12];
  const float* ffn_w2 = (const float*)d_in[13];
  const float* ffn_b2 = (const float*)d_in[14];
  const float* ln2_g  = (const float*)d_in[15];
  const float* ln2_b  = (const float*)d_in[16];
  const float* out_w  = (const float*)d_in[17];
  const float* out_b  = (const float*)d_in[18];

  char* p = (char*)d_ws;
  auto alloc = [&](size_t bytes) { char* r = p; p += (bytes + 255) & ~(size_t)255; return r; };
  short* xB    = (short*)alloc(32768ull * 384 * 2);   // x as bf16
  short* seqs  = (short*)alloc(32768ull * 128 * 2);   // Bx_t, bf16
  short* w1T   = (short*)alloc(1024ull * 384 * 2);
  short* w2T   = (short*)alloc(128ull * 1024 * 2);
  short* projB = (short*)alloc(128ull * 1024 * 2);
  short* ffn1B = (short*)alloc(1024ull * 512 * 2);
  short* ffn2B = (short*)alloc(512ull * 1024 * 2);
  short* outB  = (short*)alloc(1024ull * 1024 * 2);
  short* Spow  = (short*)alloc(12ull * 16384 * 2);
  short* SpowT = (short*)alloc(12ull * 16384 * 2);
  short* P1    = (short*)alloc(128ull * 8192 * 2);    // [i][(63-e)*128+j] = A^e
  short* P1t   = (short*)alloc(8192ull * 128 * 2);
  short* P2t   = (short*)alloc(8192ull * 128 * 2);
  float* Vz    = (float*)alloc(16ull * 512 * 128 * 4);  // per-z V partials (all written)
  // ---- zeroed zone (contiguous, all sizes 256-multiples) ----
  float* hFtail  = (float*)alloc(2ull * 8 * 128 * 4); // 8 KiB
  float* ffn1raw = (float*)alloc(8ull * 512 * 4);     // 16 KiB
  float* ffn2raw = (float*)alloc(8ull * 1024 * 4);    // 32 KiB
  // ---- end zone ----
  float* projected = (float*)alloc(8ull * 1024 * 4);

  hipMemsetAsync(hFtail, 0, (2ull * 8 * 128 + 8ull * 512 + 8ull * 1024) * 4, stream);
  hipMemsetAsync(d_out, 0, 8192ull * 4, stream);

  prep_wide<<<23104, 256, 0, stream>>>(x, enc_w1, enc_w2, proj_w, ffn_w1, ffn_w2, out_w, A,
      xB, w1T, w2T, projB, ffn1B, ffn2B, outB, P1, P1t, P2t, Spow, SpowT);
  pow_chain<<<1, 256, 0, stream>>>(Spow, SpowT);
  pow_fill<<<126, 256, 0, stream>>>(Spow, SpowT, P1, P1t, P2t);

  // fused encoder (GEMM1+GELU+GEMM2), 64-row tiles, mask-skipped
  enc_fused<<<512, 256, 0, stream>>>(xB, w1T, w2T, enc_b1, enc_b2, seqs, seq_lens);

  // recurrence: per-chunk values (per-z partials), then shifted combine + tail
  gemm_bt<<<dim3(1, 4, 16), 256, 0, stream>>>(seqs, P1, Vz, 8192, 8192, 128, 8, 512);
  combine_gemm<<<32, 256, 0, stream>>>(Vz, seqs, seq_lens, P2t, P1t, hFtail);

  // decoder
  proj_stage<<<16, 256, 0, stream>>>(hFtail, P1t, seq_lens, projB, proj_b, projected);
  ffn1_stage<<<dim3(8, 4), 256, 0, stream>>>(projected, ln1_g, ln1_b, ffn1B, ffn1raw);
  ffn2_stage<<<dim3(16, 2), 256, 0, stream>>>(ffn1raw, ffn_b1, ffn2B, ffn2raw);
  out_stage<<<dim3(16, 2), 256, 0, stream>>>(ffn2raw, ffn_b2, projected, ln2_g, ln2_b,
      outB, out_b, (float*)d_out);
}

// Round 5
// 405.433 us; speedup vs baseline: 1.7878x; 1.0578x over previous
//
#include <hip/hip_runtime.h>

// ---------- types ----------
typedef __attribute__((ext_vector_type(8))) short short8;   // 8 bf16 (4 VGPR)
typedef __attribute__((ext_vector_type(4))) short short4v;  // 4 bf16
typedef __attribute__((ext_vector_type(4))) float float4v;  // 4 fp32

__device__ __forceinline__ float bf2f(short s) {
  union { float f; unsigned u; } cv; cv.u = ((unsigned)(unsigned short)s) << 16; return cv.f;
}
__device__ __forceinline__ short f2bf(float f) {   // RNE fp32->bf16, inputs never NaN
  union { float f; unsigned u; } cv; cv.f = f;
  unsigned u = cv.u;
  unsigned r = u + 0x7FFFu + ((u >> 16) & 1u);
  return (short)(r >> 16);
}
__device__ __forceinline__ float gelu_f(float v) {
  return 0.5f * v * (1.0f + erff(v * 0.70710678118654752440f));
}
// async global->LDS, 16 B per lane; LDS dest = wave-uniform base + lane*16
__device__ __forceinline__ void glds16(const short* g, short* l) {
  __builtin_amdgcn_global_load_lds(
      (const __attribute__((address_space(1))) void*)g,
      (__attribute__((address_space(3))) void*)l, 16, 0, 0);
}

// ---------- fused encoder, 4-way nc-split ----------
// block (x=tile, y=split): accumulates GEMM2 over 2 mid-chunks, writes fp32 partial.
// LDS XOR-swizzle: tile[row][seg^(row&7)] (seg = 16B unit) -> frag reads <=2-way.
__global__ __launch_bounds__(256) void enc_fused(
    const short* __restrict__ xB, const short* __restrict__ w1T,
    const short* __restrict__ w2T, const float* __restrict__ b1,
    float* __restrict__ encP, const int* __restrict__ seq_lens)
{
  int m0 = blockIdx.x * 64;
  { int b = m0 >> 12, t = m0 & 4095; if (t >= seq_lens[b]) return; }
  int nc0 = blockIdx.y * 2;

  __shared__ __align__(16) short As[64 * 64];     // x tile, 8 KB
  __shared__ __align__(16) short Ws[128 * 64];    // w1/w2 chunk, 16 KB
  __shared__ __align__(16) short midb[64 * 128];  // GELU-mid chunk, 16 KB

  int tid = threadIdx.x, lane = tid & 63, wave = tid >> 6;
  int l15 = lane & 15, quad = lane >> 4;
  int lr = lane >> 3, lseg = lane & 7;

  float4v accO[4][2];
#pragma unroll
  for (int i = 0; i < 4; i++)
#pragma unroll
    for (int j = 0; j < 2; j++) accO[i][j] = 0;

  for (int nci = 0; nci < 2; ++nci) {
    int nc = nc0 + nci;
    float4v accM[4][2];
#pragma unroll
    for (int i = 0; i < 4; i++)
#pragma unroll
      for (int j = 0; j < 2; j++) accM[i][j] = 0;

    // ---- GEMM1 chunk: mid[64][128] = x[64][384] @ w1T[nc*128..+128][384]^T ----
    for (int ks = 0; ks < 6; ++ks) {
      int kk = ks * 64;
#pragma unroll
      for (int i = 0; i < 2; i++) {                 // x: 64 rows
        int rowg = wave * 16 + i * 8;
        glds16(xB + (size_t)(m0 + rowg + lr) * 384 + kk + (lseg ^ lr) * 8, &As[rowg * 64]);
      }
#pragma unroll
      for (int i = 0; i < 4; i++) {                 // w1 chunk: 128 rows
        int rowg = wave * 32 + i * 8;
        glds16(w1T + (size_t)(nc * 128 + rowg + lr) * 384 + kk + (lseg ^ lr) * 8, &Ws[rowg * 64]);
      }
      __syncthreads();
#pragma unroll
      for (int kh = 0; kh < 2; kh++) {
        int s = kh * 4 + quad;
        short8 af[4], bfr[2];
#pragma unroll
        for (int im = 0; im < 4; im++) {
          int r = im * 16 + l15;
          af[im] = *(short8*)&As[r * 64 + ((s ^ (r & 7)) * 8)];
        }
#pragma unroll
        for (int in = 0; in < 2; in++) {
          int r = wave * 32 + in * 16 + l15;
          bfr[in] = *(short8*)&Ws[r * 64 + ((s ^ (r & 7)) * 8)];
        }
#pragma unroll
        for (int im = 0; im < 4; im++)
#pragma unroll
          for (int in = 0; in < 2; in++)
            accM[im][in] = __builtin_amdgcn_mfma_f32_16x16x32_bf16(af[im], bfr[in], accM[im][in], 0, 0, 0);
      }
      __syncthreads();
    }
    // ---- GELU epilogue -> midb (A-operand layout, swizzled) ----
#pragma unroll
    for (int im = 0; im < 4; im++)
#pragma unroll
      for (int in = 0; in < 2; in++) {
        int k = wave * 32 + in * 16 + l15;          // mid column
        float bias = b1[nc * 128 + k];
#pragma unroll
        for (int reg = 0; reg < 4; reg++) {
          int m = im * 16 + quad * 4 + reg;
          float v = gelu_f(accM[im][in][reg] + bias);
          int s = k >> 3;
          int sw = (s & 8) | ((s & 7) ^ (m & 7));
          midb[m * 128 + sw * 8 + (k & 7)] = f2bf(v);
        }
      }
    __syncthreads();
    // ---- GEMM2 chunk: accO += mid[64][128] @ w2T[0..128][nc*128..+128]^T ----
#pragma unroll
    for (int ks2 = 0; ks2 < 2; ++ks2) {
      int kk = nc * 128 + ks2 * 64;
#pragma unroll
      for (int i = 0; i < 4; i++) {                 // w2 chunk: 128 rows (out cols)
        int rowg = wave * 32 + i * 8;
        glds16(w2T + (size_t)(rowg + lr) * 1024 + kk + (lseg ^ lr) * 8, &Ws[rowg * 64]);
      }
      __syncthreads();
#pragma unroll
      for (int kh = 0; kh < 2; kh++) {
        short8 af[4], bfr[2];
#pragma unroll
        for (int im = 0; im < 4; im++) {
          int m = im * 16 + l15;
          int kb = ks2 * 64 + kh * 32 + quad * 8;
          int s = kb >> 3;
          int sw = (s & 8) | ((s & 7) ^ (m & 7));
          af[im] = *(short8*)&midb[m * 128 + sw * 8];
        }
#pragma unroll
        for (int in = 0; in < 2; in++) {
          int r = wave * 32 + in * 16 + l15;
          int s = kh * 4 + quad;
          bfr[in] = *(short8*)&Ws[r * 64 + ((s ^ (r & 7)) * 8)];
        }
#pragma unroll
        for (int im = 0; im < 4; im++)
#pragma unroll
          for (int in = 0; in < 2; in++)
            accO[im][in] = __builtin_amdgcn_mfma_f32_16x16x32_bf16(af[im], bfr[in], accO[im][in], 0, 0, 0);
      }
      __syncthreads();
    }
  }
  // ---- write fp32 partial slice (no bias; reduce adds it) ----
  float* outp = encP + ((size_t)blockIdx.y << 22);   // 32768*128 = 1<<22
#pragma unroll
  for (int im = 0; im < 4; im++)
#pragma unroll
    for (int in = 0; in < 2; in++) {
      int n = wave * 32 + in * 16 + l15;
#pragma unroll
      for (int reg = 0; reg < 4; reg++) {
        int m = m0 + im * 16 + quad * 4 + reg;
        outp[(size_t)m * 128 + n] = accO[im][in][reg];
      }
    }
}

// ---------- enc_reduce: seqs = bf16( sum_y encP[y] + b2 ), masked tiles skipped ----------
__global__ __launch_bounds__(256) void enc_reduce(
    const float* __restrict__ encP, const float* __restrict__ b2,
    short* __restrict__ seqs, const int* __restrict__ seq_lens)
{
  int m0 = blockIdx.x * 64;
  { int b = m0 >> 12, t = m0 & 4095; if (t >= seq_lens[b]) return; }
  int t = threadIdx.x;
#pragma unroll
  for (int i = 0; i < 8; i++) {
    int f4 = t + i * 256;                   // [0,2048) float4 units in tile
    int m = m0 + (f4 >> 5);
    int cg = f4 & 31;                       // column group (4 floats)
    size_t off = (size_t)m * 128 + cg * 4;
    float4v v = *(const float4v*)&encP[off];
#pragma unroll
    for (int y = 1; y < 4; y++) {
      float4v w = *(const float4v*)&encP[((size_t)y << 22) + off];
#pragma unroll
      for (int q = 0; q < 4; q++) v[q] += w[q];
    }
    float4v bb = *(const float4v*)&b2[cg * 4];
    short4v o;
#pragma unroll
    for (int q = 0; q < 4; q++) o[q] = f2bf(v[q] + bb[q]);
    *(short4v*)&seqs[off] = o;
  }
}

// ---------- MFMA GEMM (V-GEMM): Vz[z][m][n] = sum_k A[m][k]*BT[n][k] over k-chunk z ----------
__global__ __launch_bounds__(256) void gemm_bt(
    const short* __restrict__ A_, const short* __restrict__ BT,
    float* __restrict__ out, int lda, int ldb, int ldc,
    int kSteps, int kChunk)
{
  int m0 = blockIdx.y * 128;
  int n0 = blockIdx.x * 128;
  int kBase = blockIdx.z * kChunk;

  __shared__ __align__(16) short As[128 * 64];
  __shared__ __align__(16) short Bs[128 * 64];

  int tid = threadIdx.x;
  int lane = tid & 63, wave = tid >> 6;
  int l15 = lane & 15, quad = lane >> 4;
  int wm = wave & 1, wn = wave >> 1;
  int lr = lane >> 3, lseg = lane & 7;

  float4v acc[4][4];
#pragma unroll
  for (int i = 0; i < 4; i++)
#pragma unroll
    for (int j = 0; j < 4; j++) acc[i][j] = 0;

  for (int ks = 0; ks < kSteps; ++ks) {
    int kk = kBase + ks * 64;
#pragma unroll
    for (int i = 0; i < 4; i++) {
      int rowg = wave * 32 + i * 8;
      glds16(A_ + (size_t)(m0 + rowg + lr) * lda + kk + (lseg ^ lr) * 8, &As[rowg * 64]);
      glds16(BT + (size_t)(n0 + rowg + lr) * ldb + kk + (lseg ^ lr) * 8, &Bs[rowg * 64]);
    }
    __syncthreads();
#pragma unroll
    for (int kh = 0; kh < 2; kh++) {
      int s = kh * 4 + quad;
      short8 af[4], bfr[4];
#pragma unroll
      for (int im = 0; im < 4; im++) {
        int r = wm * 64 + im * 16 + l15;
        af[im] = *(short8*)&As[r * 64 + ((s ^ (r & 7)) * 8)];
      }
#pragma unroll
      for (int in = 0; in < 4; in++) {
        int r = wn * 64 + in * 16 + l15;
        bfr[in] = *(short8*)&Bs[r * 64 + ((s ^ (r & 7)) * 8)];
      }
#pragma unroll
      for (int im = 0; im < 4; im++)
#pragma unroll
        for (int in = 0; in < 4; in++)
          acc[im][in] = __builtin_amdgcn_mfma_f32_16x16x32_bf16(af[im], bfr[in], acc[im][in], 0, 0, 0);
    }
    __syncthreads();
  }
  float* outz = out + (size_t)blockIdx.z * 65536;
#pragma unroll
  for (int im = 0; im < 4; im++)
#pragma unroll
    for (int in = 0; in < 4; in++) {
      int n = n0 + wn * 64 + in * 16 + l15;
#pragma unroll
      for (int reg = 0; reg < 4; reg++) {
        int m = m0 + wm * 64 + im * 16 + quad * 4 + reg;
        outz[(size_t)m * ldc + n] = acc[im][in][reg];
      }
    }
}

// ---------- prep: x->bf16 (mask-skipped), weight conversions, identity/A seeds ----------
__global__ void prep_wide(const float* __restrict__ x, const float* __restrict__ w1,
                          const float* __restrict__ w2,
                          const float* __restrict__ proj_w, const float* __restrict__ ffn_w1,
                          const float* __restrict__ ffn_w2, const float* __restrict__ out_w,
                          const float* __restrict__ A, const int* __restrict__ seq_lens,
                          short* __restrict__ xB,
                          short* __restrict__ w1T, short* __restrict__ w2T,
                          short* __restrict__ projB, short* __restrict__ ffn1B,
                          short* __restrict__ ffn2B, short* __restrict__ outB,
                          short* __restrict__ P1, short* __restrict__ P1t,
                          short* __restrict__ P2t,
                          short* __restrict__ Spow, short* __restrict__ SpowT)
{
  int idx = blockIdx.x * 256 + threadIdx.x;
  if (idx < 3145728) {                       // x -> bf16 (float4 units), skip masked rows
    int row = idx / 96;                      // 384 floats = 96 float4 per row
    int t = row & 4095, b = row >> 12;
    if (t >= seq_lens[b]) return;            // xB stays poison there (never used)
    float4v v = ((const float4v*)x)[idx];
    short4v o;
#pragma unroll
    for (int j = 0; j < 4; j++) o[j] = f2bf(v[j]);
    ((short4v*)xB)[idx] = o;
    return;
  }
  idx -= 3145728;
  if (idx < 393216) {                        // w1T[n][k] = w1[k][n]
    int n = idx / 384, k = idx % 384;
    w1T[idx] = f2bf(w1[k * 1024 + n]);
    return;
  }
  idx -= 393216;
  if (idx < 131072) {                        // w2T[n][k] = w2[k][n]
    int n = idx / 1024, k = idx % 1024;
    w2T[idx] = f2bf(w2[k * 128 + n]);
    return;
  }
  idx -= 131072;
  if (idx < 131072) { projB[idx] = f2bf(proj_w[idx]); return; }
  idx -= 131072;
  if (idx < 524288) { ffn1B[idx] = f2bf(ffn_w1[idx]); return; }
  idx -= 524288;
  if (idx < 524288) { ffn2B[idx] = f2bf(ffn_w2[idx]); return; }
  idx -= 524288;
  if (idx < 1048576) { outB[idx] = f2bf(out_w[idx]); return; }
  idx -= 1048576;
  if (idx < 16384) {                         // identity slots (e=0) + A seed
    int i = idx >> 7, j = idx & 127;
    short bidv = f2bf((i == j) ? 1.0f : 0.0f);
    P1[i * 8192 + 63 * 128 + j] = bidv;
    P1t[(63 * 128 + j) * 128 + i] = bidv;
    P2t[(63 * 128 + j) * 128 + i] = bidv;
    short ab = f2bf(A[idx]);
    Spow[idx] = ab;                          // A^1 row-major
    SpowT[(size_t)j * 128 + i] = ab;         // transposed
  }
}

// ---------- single-block MFMA squaring chain ----------
// Spow[k]: k=0..6 -> A^(2^k); k=7..11 -> (A^64)^(2^(k-6)).
__global__ __launch_bounds__(256) void pow_chain(short* __restrict__ Spow,
                                                 short* __restrict__ SpowT)
{
  __shared__ short X[16384];    // cur, row-major
  __shared__ short XT[16384];   // cur, transposed
  int t = threadIdx.x;
  for (int i = t * 8; i < 16384; i += 2048) {
    *(short8*)&X[i]  = *(const short8*)&Spow[i];
    *(short8*)&XT[i] = *(const short8*)&SpowT[i];
  }
  __syncthreads();
  int lane = t & 63, wave = t >> 6, l15 = lane & 15, quad = lane >> 4;
  for (int step = 1; step <= 11; ++step) {
    short8 af[2][4], bfr[8][4];
#pragma unroll
    for (int mt = 0; mt < 2; mt++)
#pragma unroll
      for (int ks = 0; ks < 4; ks++)
        af[mt][ks] = *(short8*)&X[(wave * 32 + mt * 16 + l15) * 128 + ks * 32 + quad * 8];
#pragma unroll
    for (int nt = 0; nt < 8; nt++)
#pragma unroll
      for (int ks = 0; ks < 4; ks++)
        bfr[nt][ks] = *(short8*)&XT[(nt * 16 + l15) * 128 + ks * 32 + quad * 8];
    __syncthreads();                       // all frag loads done before in-place overwrite
    float4v acc[2][8];
#pragma unroll
    for (int mt = 0; mt < 2; mt++)
#pragma unroll
      for (int nt = 0; nt < 8; nt++) acc[mt][nt] = 0;
#pragma unroll
    for (int ks = 0; ks < 4; ks++)
#pragma unroll
      for (int mt = 0; mt < 2; mt++)
#pragma unroll
        for (int nt = 0; nt < 8; nt++)
          acc[mt][nt] = __builtin_amdgcn_mfma_f32_16x16x32_bf16(af[mt][ks], bfr[nt][ks], acc[mt][nt], 0, 0, 0);
    short* gX  = Spow  + (size_t)step * 16384;
    short* gXT = SpowT + (size_t)step * 16384;
#pragma unroll
    for (int mt = 0; mt < 2; mt++)
#pragma unroll
      for (int nt = 0; nt < 8; nt++)
#pragma unroll
        for (int reg = 0; reg < 4; reg++) {
          int m = wave * 32 + mt * 16 + quad * 4 + reg;
          int n = nt * 16 + l15;
          short v = f2bf(acc[mt][nt][reg]);
          X[m * 128 + n] = v; XT[n * 128 + m] = v;
          gX[m * 128 + n] = v; gXT[n * 128 + m] = v;
        }
    __syncthreads();
  }
}

// ---------- wide fill: block computes one table slot via seed-product chain ----------
__global__ __launch_bounds__(256) void pow_fill(const short* __restrict__ Spow,
                                                const short* __restrict__ SpowT,
                                                short* __restrict__ P1,
                                                short* __restrict__ P1t,
                                                short* __restrict__ P2t)
{
  __shared__ short cur[16384];
  __shared__ short Bt[16384];
  int bid = blockIdx.x;
  int table1 = bid < 63;
  int e = table1 ? bid + 1 : bid - 62;
  int t = threadIdx.x;
  int lane = t & 63, wave = t >> 6, l15 = lane & 15, quad = lane >> 4;

  int bits = e;
  int k0 = __ffs(bits) - 1; bits &= bits - 1;
  int s0 = table1 ? k0 : (k0 == 0 ? 6 : 6 + k0);
  for (int i = t * 8; i < 16384; i += 2048)
    *(short8*)&cur[i] = *(const short8*)&Spow[(size_t)s0 * 16384 + i];

  while (bits) {
    int k = __ffs(bits) - 1; bits &= bits - 1;
    int si = table1 ? k : (k == 0 ? 6 : 6 + k);
    for (int i = t * 8; i < 16384; i += 2048)
      *(short8*)&Bt[i] = *(const short8*)&SpowT[(size_t)si * 16384 + i];
    __syncthreads();
    short8 af[2][4], bfr[8][4];
#pragma unroll
    for (int mt = 0; mt < 2; mt++)
#pragma unroll
      for (int ks = 0; ks < 4; ks++)
        af[mt][ks] = *(short8*)&cur[(wave * 32 + mt * 16 + l15) * 128 + ks * 32 + quad * 8];
#pragma unroll
    for (int nt = 0; nt < 8; nt++)
#pragma unroll
      for (int ks = 0; ks < 4; ks++)
        bfr[nt][ks] = *(short8*)&Bt[(nt * 16 + l15) * 128 + ks * 32 + quad * 8];
    __syncthreads();                       // loads done before in-place write of cur
    float4v acc[2][8];
#pragma unroll
    for (int mt = 0; mt < 2; mt++)
#pragma unroll
      for (int nt = 0; nt < 8; nt++) acc[mt][nt] = 0;
#pragma unroll
    for (int ks = 0; ks < 4; ks++)
#pragma unroll
      for (int mt = 0; mt < 2; mt++)
#pragma unroll
        for (int nt = 0; nt < 8; nt++)
          acc[mt][nt] = __builtin_amdgcn_mfma_f32_16x16x32_bf16(af[mt][ks], bfr[nt][ks], acc[mt][nt], 0, 0, 0);
#pragma unroll
    for (int mt = 0; mt < 2; mt++)
#pragma unroll
      for (int nt = 0; nt < 8; nt++)
#pragma unroll
        for (int reg = 0; reg < 4; reg++) {
          int m = wave * 32 + mt * 16 + quad * 4 + reg;
          int n = nt * 16 + l15;
          cur[m * 128 + n] = f2bf(acc[mt][nt][reg]);
        }
    __syncthreads();
  }
  __syncthreads();
  int slot = 63 - e;
  for (int idx = t; idx < 16384; idx += 256) {
    int i = idx >> 7, j = idx & 127;
    short v = cur[idx];
    if (table1) {
      P1[i * 8192 + slot * 128 + j] = v;
      P1t[(slot * 128 + j) * 128 + i] = v;
    } else {
      P2t[(slot * 128 + j) * 128 + i] = v;
    }
  }
}

// ---------- combine: build shifted inputs in LDS (z-sum of Vz / tail from seqs) + GEMM ----------
// blocks: pp in {0:hF via P2, 1:tail via P1} x 32 k-slices of 256
__global__ __launch_bounds__(256) void combine_gemm(
    const float* __restrict__ Vz, const short* __restrict__ seqs,
    const int* __restrict__ seq_lens,
    const short* __restrict__ P2t, const short* __restrict__ P1t,
    float* __restrict__ hFtail)
{
  __shared__ short X[256 * 8];   // [k_local][b] bf16
  int pp = blockIdx.x >> 5, ks = blockIdx.x & 31;
  int t = threadIdx.x;
  for (int e = t; e < 2048; e += 256) {
    int klocal = e >> 3, b = e & 7;
    int cp = ks * 2 + (klocal >> 7), i = klocal & 127;
    int L = seq_lens[b];
    if (pp == 0) {
      int F = L >> 6, sh = 64 - F;
      float v = 0.f;
      if (cp >= sh) {
        int row = (b * 64 + (cp - sh)) * 128 + i;
#pragma unroll
        for (int z = 0; z < 32; z++) v += Vz[(size_t)z * 65536 + row];
      }
      X[e] = f2bf(v);
    } else {
      int F = L >> 6, rr = L & 63, sh = 64 - rr;
      short s = 0;
      if (cp >= sh) s = seqs[((size_t)b * 4096 + F * 64 + (cp - sh)) * 128 + i];
      X[e] = s;
    }
  }
  __syncthreads();
  const short* P = pp ? P1t : P2t;
  float* outp = hFtail + pp * 1024;
  int i = t & 127, g = t >> 7;
  float acc[4] = {0, 0, 0, 0};
  for (int kl = 0; kl < 256; ++kl) {
    int k = ks * 256 + kl;
    float pv = bf2f(P[k * 128 + i]);
    short4v xv = *(const short4v*)(X + kl * 8 + g * 4);
#pragma unroll
    for (int q = 0; q < 4; q++) acc[q] += bf2f(xv[q]) * pv;
  }
#pragma unroll
  for (int q = 0; q < 4; q++) atomicAdd(&outp[(g * 4 + q) * 128 + i], acc[q]);
}

// ---------- decoder stage 1: h = A^rr hF + tail, proj matvec ----------
__global__ __launch_bounds__(256) void proj_stage(
    const float* __restrict__ hFtail, const short* __restrict__ P1t,
    const int* __restrict__ seq_lens, const short* __restrict__ projB,
    const float* __restrict__ proj_b, float* __restrict__ projected)
{
  __shared__ short hT[128 * 8];        // bf16 [k][b]
  __shared__ float red[4][64][8];
  int t = threadIdx.x;
  {
    int b = t >> 5, i4 = (t & 31) * 4;
    int rr = seq_lens[b] & 63;
    const short* M = P1t + (size_t)(63 - rr) * 128 * 128;   // (A^rr)[i][j] = M[j*128+i]
    const float* hF = hFtail + b * 128;
    float acc[4];
#pragma unroll
    for (int q = 0; q < 4; q++) acc[q] = hFtail[1024 + b * 128 + i4 + q];  // tail
    for (int j = 0; j < 128; ++j) {
      float hv = hF[j];
      short4v mv = *(const short4v*)&M[j * 128 + i4];
#pragma unroll
      for (int q = 0; q < 4; q++) acc[q] += bf2f(mv[q]) * hv;
    }
#pragma unroll
    for (int q = 0; q < 4; q++) hT[(i4 + q) * 8 + b] = f2bf(acc[q]);
  }
  __syncthreads();
  int c = t & 63, sl = t >> 6;
  int n = blockIdx.x * 64 + c;
  float acc[8] = {0, 0, 0, 0, 0, 0, 0, 0};
  for (int k = sl * 32; k < sl * 32 + 32; ++k) {
    short8 xv = *(short8*)&hT[k * 8];
    float wv = bf2f(projB[k * 1024 + n]);
#pragma unroll
    for (int b = 0; b < 8; b++) acc[b] += bf2f(xv[b]) * wv;
  }
#pragma unroll
  for (int b = 0; b < 8; b++) red[sl][c][b] = acc[b];
  __syncthreads();
  if (sl == 0) {
#pragma unroll
    for (int s = 1; s < 4; s++)
#pragma unroll
      for (int b = 0; b < 8; b++) acc[b] += red[s][c][b];
    float bn = proj_b[n];
#pragma unroll
    for (int b = 0; b < 8; b++) projected[b * 1024 + n] = acc[b] + bn;
  }
}

// ---------- decoder stage 2: LN1(projected) @ ffn_w1 -> ffn1raw ----------
__global__ __launch_bounds__(256) void ffn1_stage(
    const float* __restrict__ projected, const float* __restrict__ g1,
    const float* __restrict__ b1, const short* __restrict__ ffn1B,
    float* __restrict__ ffn1raw)
{
  __shared__ float part[8][32][2];
  __shared__ float stats[8][2];
  __shared__ short xT[256 * 8];
  __shared__ float red[4][64][8];
  int t = threadIdx.x;
  { int b = t >> 5, j0 = t & 31; float s = 0, q = 0;
    for (int k = j0 * 32; k < j0 * 32 + 32; ++k) { float v = projected[b * 1024 + k]; s += v; q += v * v; }
    part[b][j0][0] = s; part[b][j0][1] = q; }
  __syncthreads();
  if (t < 8) {
    float s = 0, q = 0;
    for (int j = 0; j < 32; j++) { s += part[t][j][0]; q += part[t][j][1]; }
    float mu = s * (1.0f / 1024.0f);
    float var = q * (1.0f / 1024.0f) - mu * mu;
    stats[t][0] = mu; stats[t][1] = rsqrtf(var + 1e-5f);
  }
  __syncthreads();
  int ky0 = blockIdx.y * 256;
  for (int idx = t; idx < 2048; idx += 256) {
    int kl = idx >> 3, b = idx & 7; int k = ky0 + kl;
    float v = (projected[b * 1024 + k] - stats[b][0]) * stats[b][1] * g1[k] + b1[k];
    xT[kl * 8 + b] = f2bf(v);
  }
  __syncthreads();
  int c = t & 63, sl = t >> 6;
  int n = blockIdx.x * 64 + c;
  float acc[8] = {0, 0, 0, 0, 0, 0, 0, 0};
  for (int kl = sl * 64; kl < sl * 64 + 64; ++kl) {
    short8 xv = *(short8*)&xT[kl * 8];
    float wv = bf2f(ffn1B[(size_t)(ky0 + kl) * 512 + n]);
#pragma unroll
    for (int b = 0; b < 8; b++) acc[b] += bf2f(xv[b]) * wv;
  }
#pragma unroll
  for (int b = 0; b < 8; b++) red[sl][c][b] = acc[b];
  __syncthreads();
  if (sl == 0) {
#pragma unroll
    for (int s = 1; s < 4; s++)
#pragma unroll
      for (int b = 0; b < 8; b++) acc[b] += red[s][c][b];
#pragma unroll
    for (int b = 0; b < 8; b++) atomicAdd(&ffn1raw[b * 512 + n], acc[b]);
  }
}

// ---------- decoder stage 3: gelu(ffn1raw + b1) @ ffn_w2 -> ffn2raw ----------
__global__ __launch_bounds__(256) void ffn2_stage(
    const float* __restrict__ ffn1raw, const float* __restrict__ fb1,
    const short* __restrict__ ffn2B, float* __restrict__ ffn2raw)
{
  __shared__ short xT[256 * 8];
  __shared__ float red[4][64][8];
  int t = threadIdx.x;
  int ky0 = blockIdx.y * 256;
  for (int idx = t; idx < 2048; idx += 256) {
    int kl = idx >> 3, b = idx & 7; int k = ky0 + kl;
    float v = gelu_f(ffn1raw[b * 512 + k] + fb1[k]);
    xT[kl * 8 + b] = f2bf(v);
  }
  __syncthreads();
  int c = t & 63, sl = t >> 6;
  int n = blockIdx.x * 64 + c;
  float acc[8] = {0, 0, 0, 0, 0, 0, 0, 0};
  for (int kl = sl * 64; kl < sl * 64 + 64; ++kl) {
    short8 xv = *(short8*)&xT[kl * 8];
    float wv = bf2f(ffn2B[(size_t)(ky0 + kl) * 1024 + n]);
#pragma unroll
    for (int b = 0; b < 8; b++) acc[b] += bf2f(xv[b]) * wv;
  }
#pragma unroll
  for (int b = 0; b < 8; b++) red[sl][c][b] = acc[b];
  __syncthreads();
  if (sl == 0) {
#pragma unroll
    for (int s = 1; s < 4; s++)
#pragma unroll
      for (int b = 0; b < 8; b++) acc[b] += red[s][c][b];
#pragma unroll
    for (int b = 0; b < 8; b++) atomicAdd(&ffn2raw[b * 1024 + n], acc[b]);
  }
}

// ---------- decoder stage 4: LN2(ffn2raw + b2 + projected) @ out_w + out_b -> d_out ----------
__global__ __launch_bounds__(256) void out_stage(
    const float* __restrict__ ffn2raw, const float* __restrict__ fb2,
    const float* __restrict__ projected, const float* __restrict__ g2,
    const float* __restrict__ b2ln, const short* __restrict__ outB,
    const float* __restrict__ out_b, float* __restrict__ d_out)
{
  __shared__ float part[8][32][2];
  __shared__ float stats[8][2];
  __shared__ short xT[512 * 8];
  __shared__ float red[4][64][8];
  int t = threadIdx.x;
  { int b = t >> 5, j0 = t & 31; float s = 0, q = 0;
    for (int k = j0 * 32; k < j0 * 32 + 32; ++k) {
      float v = ffn2raw[b * 1024 + k] + fb2[k] + projected[b * 1024 + k];
      s += v; q += v * v;
    }
    part[b][j0][0] = s; part[b][j0][1] = q; }
  __syncthreads();
  if (t < 8) {
    float s = 0, q = 0;
    for (int j = 0; j < 32; j++) { s += part[t][j][0]; q += part[t][j][1]; }
    float mu = s * (1.0f / 1024.0f);
    float var = q * (1.0f / 1024.0f) - mu * mu;
    stats[t][0] = mu; stats[t][1] = rsqrtf(var + 1e-5f);
  }
  __syncthreads();
  int ky0 = blockIdx.y * 512;
  for (int idx = t; idx < 4096; idx += 256) {
    int kl = idx >> 3, b = idx & 7; int k = ky0 + kl;
    float v = ffn2raw[b * 1024 + k] + fb2[k] + projected[b * 1024 + k];
    v = (v - stats[b][0]) * stats[b][1] * g2[k] + b2ln[k];
    xT[kl * 8 + b] = f2bf(v);
  }
  __syncthreads();
  int c = t & 63, sl = t >> 6;
  int n = blockIdx.x * 64 + c;
  float acc[8] = {0, 0, 0, 0, 0, 0, 0, 0};
  for (int kl = sl * 128; kl < sl * 128 + 128; ++kl) {
    short8 xv = *(short8*)&xT[kl * 8];
    float wv = bf2f(outB[(size_t)(ky0 + kl) * 1024 + n]);
#pragma unroll
    for (int b = 0; b < 8; b++) acc[b] += bf2f(xv[b]) * wv;
  }
#pragma unroll
  for (int b = 0; b < 8; b++) red[sl][c][b] = acc[b];
  __syncthreads();
  if (sl == 0) {
#pragma unroll
    for (int s = 1; s < 4; s++)
#pragma unroll
      for (int b = 0; b < 8; b++) acc[b] += red[s][c][b];
    float bn = (blockIdx.y == 0) ? out_b[n] : 0.0f;
#pragma unroll
    for (int b = 0; b < 8; b++) atomicAdd(&d_out[b * 1024 + n], acc[b] + bn);
  }
}

// ---------- host ----------
extern "C" void kernel_launch(void* const* d_in, const int* in_sizes, int n_in,
                              void* d_out, int out_size, void* d_ws, size_t ws_size,
                              hipStream_t stream)
{
  (void)in_sizes; (void)n_in; (void)out_size; (void)ws_size;
  const float* x      = (const float*)d_in[0];
  const int* seq_lens = (const int*)d_in[1];
  const float* A      = (const float*)d_in[2];
  const float* enc_w1 = (const float*)d_in[3];
  const float* enc_b1 = (const float*)d_in[4];
  const float* enc_w2 = (const float*)d_in[5];
  const float* enc_b2 = (const float*)d_in[6];
  const float* proj_w = (const float*)d_in[7];
  const float* proj_b = (const float*)d_in[8];
  const float* ln1_g  = (const float*)d_in[9];
  const float* ln1_b  = (const float*)d_in[10];
  const float* ffn_w1 = (const float*)d_in[11];
  const float* ffn_b1 = (const float*)d_in[12];
  const float* ffn_w2 = (const float*)d_in[13];
  const float* ffn_b2 = (const float*)d_in[14];
  const float* ln2_g  = (const float*)d_in[15];
  const float* ln2_b  = (const float*)d_in[16];
  const float* out_w  = (const float*)d_in[17];
  const float* out_b  = (const float*)d_in[18];

  char* p = (char*)d_ws;
  auto alloc = [&](size_t bytes) { char* r = p; p += (bytes + 255) & ~(size_t)255; return r; };
  short* xB    = (short*)alloc(32768ull * 384 * 2);     // 25 MB
  float* encP  = (float*)alloc(4ull * 32768 * 128 * 4); // 64 MB partials
  short* seqs  = (short*)alloc(32768ull * 128 * 2);     // 8.4 MB
  short* w1T   = (short*)alloc(1024ull * 384 * 2);
  short* w2T   = (short*)alloc(128ull * 1024 * 2);
  short* projB = (short*)alloc(128ull * 1024 * 2);
  short* ffn1B = (short*)alloc(1024ull * 512 * 2);
  short* ffn2B = (short*)alloc(512ull * 1024 * 2);
  short* outB  = (short*)alloc(1024ull * 1024 * 2);
  short* Spow  = (short*)alloc(12ull * 16384 * 2);
  short* SpowT = (short*)alloc(12ull * 16384 * 2);
  short* P1    = (short*)alloc(128ull * 8192 * 2);      // [i][(63-e)*128+j] = A^e
  short* P1t   = (short*)alloc(8192ull * 128 * 2);
  short* P2t   = (short*)alloc(8192ull * 128 * 2);
  float* Vz    = (float*)alloc(32ull * 512 * 128 * 4);  // 8.4 MB per-z V partials
  // ---- zeroed zone (contiguous, all sizes 256-multiples) ----
  float* hFtail  = (float*)alloc(2ull * 8 * 128 * 4);
  float* ffn1raw = (float*)alloc(8ull * 512 * 4);
  float* ffn2raw = (float*)alloc(8ull * 1024 * 4);
  // ---- end zone ----
  float* projected = (float*)alloc(8ull * 1024 * 4);

  hipMemsetAsync(hFtail, 0, (2ull * 8 * 128 + 8ull * 512 + 8ull * 1024) * 4, stream);
  hipMemsetAsync(d_out, 0, 8192ull * 4, stream);

  prep_wide<<<23104, 256, 0, stream>>>(x, enc_w1, enc_w2, proj_w, ffn_w1, ffn_w2, out_w, A,
      seq_lens, xB, w1T, w2T, projB, ffn1B, ffn2B, outB, P1, P1t, P2t, Spow, SpowT);
  pow_chain<<<1, 256, 0, stream>>>(Spow, SpowT);
  pow_fill<<<126, 256, 0, stream>>>(Spow, SpowT, P1, P1t, P2t);

  // fused encoder: 4-way nc-split partials, then reduce (+b2) -> bf16 seqs
  enc_fused<<<dim3(512, 4), 256, 0, stream>>>(xB, w1T, w2T, enc_b1, encP, seq_lens);
  enc_reduce<<<512, 256, 0, stream>>>(encP, enc_b2, seqs, seq_lens);

  // recurrence: per-chunk values (32-way z partials), then shifted combine + tail
  gemm_bt<<<dim3(1, 4, 32), 256, 0, stream>>>(seqs, P1, Vz, 8192, 8192, 128, 4, 256);
  combine_gemm<<<64, 256, 0, stream>>>(Vz, seqs, seq_lens, P2t, P1t, hFtail);

  // decoder
  proj_stage<<<16, 256, 0, stream>>>(hFtail, P1t, seq_lens, projB, proj_b, projected);
  ffn1_stage<<<dim3(8, 4), 256, 0, stream>>>(projected, ln1_g, ln1_b, ffn1B, ffn1raw);
  ffn2_stage<<<dim3(16, 2), 256, 0, stream>>>(ffn1raw, ffn_b1, ffn2B, ffn2raw);
  out_stage<<<dim3(16, 2), 256, 0, stream>>>(ffn2raw, ffn_b2, projected, ln2_g, ln2_b,
      outB, out_b, (float*)d_out);
}